// Round 4
// baseline (503.110 us; speedup 1.0000x reference)
//
#include <hip/hip_runtime.h>
#include <hip/hip_fp16.h>

#define SEQ    128
#define NTL    512               /* n-tiles of 16 */
#define TOT    (SEQ*8192)        /* 1048576 */
#define T3     (TOT*3)

typedef __attribute__((ext_vector_type(8))) _Float16 half8;
typedef __attribute__((ext_vector_type(4))) float    f32x4;
union H8 { half8 v; ushort s[8]; uint u[4]; };

__device__ __forceinline__ float siluf(float x){ return x/(1.f+__expf(-x)); }
__device__ __forceinline__ ushort f2h(float x){ _Float16 h=(_Float16)x; return __builtin_bit_cast(ushort,h); }
__device__ __forceinline__ float  h2fl(ushort u){ _Float16 h=__builtin_bit_cast(_Float16,u); return (float)h; }
__device__ __forceinline__ float  lo16(uint u){ return h2fl((ushort)(u&0xFFFFu)); }
__device__ __forceinline__ float  hi16(uint u){ return h2fl((ushort)(u>>16)); }
__device__ __forceinline__ uint   pkf(float a, float b){ auto r=__builtin_amdgcn_cvt_pkrtz(a,b); return __builtin_bit_cast(uint,r); }
__device__ __forceinline__ uint   shflx(uint v, int m){ return (uint)__shfl_xor((int)v, m, 64); }

// C-layout per-lane stream (v_t = value of unit 4t+q) -> MFMA B-fragment (k=unit, bias@k=20).
// Verified structure from R3 (absmax-passing).
__device__ __forceinline__ half8 xpose(int q, float v0,float v1,float v2,float v3,float v4,float vb){
    const bool qb0=(q&1)!=0, qb1=(q&2)!=0;
    uint M0 = pkf(v0,v1), M1 = pkf(v2,v3), M2 = pkf(v4,vb);
    uint t0 = shflx(M1,16), t1 = shflx(M0,16), t3 = shflx(M2,16);
    uint A0 = qb0? t0:M0, A1 = qb0? M1:t1, A2 = qb0? 0u:M2, A3 = qb0? 0u:t3;
    uint s0 = shflx(A2,32), s1 = shflx(A3,32), s2 = shflx(A0,32), s3 = shflx(A1,32);
    uint R0 = qb1? s0:A0, R1 = qb1? s1:A1, R2 = qb1? A2:s2, R3 = qb1? A3:s3;
    H8 o;
    o.u[0]=(R0&0xFFFFu)|(R1<<16);
    o.u[1]=(R2&0xFFFFu)|(R3<<16);
    o.u[2]=(R0>>16)|(R1&0xFFFF0000u);
    o.u[3]=(R2>>16)|(R3&0xFFFF0000u);
    return o.v;
}

// gates pre-scaled by -1/ln2 (-2/ln2 for g row): pure exp2/rcp
__device__ __forceinline__ float gate_step(const f32x4 a, float& c){
    const float ei=__builtin_amdgcn_exp2f(a[0]);
    const float ef=__builtin_amdgcn_exp2f(a[1]);
    const float eg=__builtin_amdgcn_exp2f(a[2]);
    const float eo=__builtin_amdgcn_exp2f(a[3]);
    const float gi=__builtin_amdgcn_rcpf(1.f+ei);
    const float gf=__builtin_amdgcn_rcpf(1.f+ef);
    const float gg=2.f*__builtin_amdgcn_rcpf(1.f+eg)-1.f;
    const float go=__builtin_amdgcn_rcpf(1.f+eo);
    c = gf*c + gi*gg;
    const float ec=__builtin_amdgcn_exp2f(-2.885390082f*c);
    return go*(2.f*__builtin_amdgcn_rcpf(1.f+ec)-1.f);
}

__device__ __forceinline__ void red4(float& s, float& ss){
    s  += __shfl_xor(s,16,64);  s  += __shfl_xor(s,32,64);
    ss += __shfl_xor(ss,16,64); ss += __shfl_xor(ss,32,64);
}

// unit mapping for 20-row GEMV tiles: tile0 row m -> unit 4*(m&3)+(m>>2)  (C reg r = unit 4r+q)
//                                     tile1 row m -> unit 16+(m>>2) iff (m&3)==0 (C reg 0 = unit 16+q)
__device__ __forceinline__ int uemap(int tt, int m){
    if (tt==0) return 4*(m&3)+(m>>2);
    return ((m&3)==0) ? 16+(m>>2) : -1;
}

__global__ __launch_bounds__(128) void k_fused(
    const float* __restrict__ xlni, const float* __restrict__ imean, const float* __restrict__ istd,
    const float* __restrict__ w1,  const float* __restrict__ b1,  const float* __restrict__ g1,
    const float* __restrict__ w2,  const float* __restrict__ b2,  const float* __restrict__ g2,
    const float* __restrict__ wih1, const float* __restrict__ whh1,
    const float* __restrict__ bih1, const float* __restrict__ bhh1,
    const float* __restrict__ ln3g, const float* __restrict__ ln3b,
    const float* __restrict__ wih2, const float* __restrict__ whh2,
    const float* __restrict__ bih2, const float* __restrict__ bhh2,
    const float* __restrict__ g4, const float* __restrict__ w3, const float* __restrict__ b3,
    const float* __restrict__ g5, const float* __restrict__ w4, const float* __restrict__ b4,
    const float* __restrict__ g6, const float* __restrict__ w5, const float* __restrict__ b5,
    const float* __restrict__ wfw, const float* __restrict__ wfb,
    const float* __restrict__ sfw, const float* __restrict__ sfb,
    const float* __restrict__ dfw, const float* __restrict__ dfb,
    float* __restrict__ out)
{
    __shared__ float sxl[SEQ*48];          // per-tile xlni slice [l][col][3]
    __shared__ uint4 sFr[2][64];           // x3n B-fragments, double-buffered
    __shared__ uint  sPx[2][64][3];        // raw x3 (packed halves)

    const int tid  = threadIdx.x;
    const int wid  = tid >> 6;
    const int lane = tid & 63;
    const int col  = lane & 15, q = lane >> 4;
    const int nt   = blockIdx.x;
    const f32x4 Z  = {0.f,0.f,0.f,0.f};

    // stage this tile's xlni into LDS (both waves)
    for (int i = tid; i < SEQ*48; i += 128)
        sxl[i] = xlni[(size_t)(i/48)*24576 + (size_t)nt*48 + (i%48)];

    if (wid == 0){
        // ================= WAVE A: preprocess + LSTM1 (producer) =================
        // -- stage weights
        half8 Aih1[5], Ahh1[5];
#pragma unroll
        for (int t=0;t<5;t++){
            const int M = t*16 + col, u = M>>2, g = M&3, r = g*20+u;
            const float sc = (g==2)? -2.885390082f : -1.442695041f;
            H8 a,h;
#pragma unroll
            for (int j=0;j<8;j++){
                const int k = q*8+j;
                float va=0.f, vh=0.f;
                if (k<20){ va = wih1[r*20+k]*g2[k]*sc; vh = whh1[r*20+k]*sc; }
                else if (k==20){ va = (bih1[r]+bhh1[r])*sc; }
                a.s[j]=f2h(va); h.s[j]=f2h(vh);
            }
            Aih1[t]=a.v; Ahh1[t]=h.v;
        }
        half8 Aw2[2];
#pragma unroll
        for (int tt=0;tt<2;tt++){
            const int u = uemap(tt, col);
            H8 a;
#pragma unroll
            for (int j=0;j<8;j++){
                const int k = q*8+j;
                float v=0.f;
                if (u>=0){ if (k<20) v = w2[u*20+k]*g1[k]; else if (k==20) v = b2[u]; }
                a.s[j]=f2h(v);
            }
            Aw2[tt]=a.v;
        }
        float wd[5], wu[5], ws0[5], ws1[5], ws2[5], ws3[5];
#pragma unroll
        for (int t=0;t<5;t++){
            const int u = 4*t+q;
            wd[t]=w1[u*6+0]; wu[t]=w1[u*6+1];
            ws0[t]=w1[u*6+2]+b1[u]; ws1[t]=w1[u*6+3]+b1[u];
            ws2[t]=w1[u*6+4]+b1[u]; ws3[t]=w1[u*6+5]+b1[u];
        }
        const float mu0=imean[0], mu1=imean[1];
        const float ri0=1.f/istd[0], ri1=1.f/istd[1];

        const float bsl = (q==0)? 1.0f : 0.0f;

        // PRE(l): preprocessing -> lin1 -> ln1 -> lin2(MFMA) -> silu -> ln2
        auto PRE = [&](int l, half8& xnf, float* X2o){
            const float d0 = sxl[l*48+col*3+0];
            const float d1 = sxl[l*48+col*3+1];
            const float rr = sxl[l*48+col*3+2];
            const float xd = (__logf(1e-5f+d0)-mu0)*ri0;
            const float xu = (__logf(fminf(fmaxf(d1,100.f),60000.f))-mu1)*ri1;
            int r = (int)fmaxf(rr,1.f)-1; r = r<0?0:(r>3?3:r);
            float av[5], s=0.f, ss=0.f;
#pragma unroll
            for (int t=0;t<5;t++){
                const float wsel = (r==0)?ws0[t]:(r==1)?ws1[t]:(r==2)?ws2[t]:ws3[t];
                const float v = wd[t]*xd + wu[t]*xu + wsel;
                av[t]=siluf(v); s+=av[t]; ss+=av[t]*av[t];
            }
            red4(s,ss);
            float mn=s*0.05f, var=fmaxf(ss*0.05f-mn*mn,0.f);
            float rs=__builtin_amdgcn_rsqf(var+1e-5f); float mr=mn*rs;
            const half8 yf = xpose(q, av[0]*rs-mr, av[1]*rs-mr, av[2]*rs-mr, av[3]*rs-mr, av[4]*rs-mr, bsl);
            const f32x4 c0 = __builtin_amdgcn_mfma_f32_16x16x32_f16(Aw2[0], yf, Z, 0,0,0);
            const f32x4 c1 = __builtin_amdgcn_mfma_f32_16x16x32_f16(Aw2[1], yf, Z, 0,0,0);
            s=0.f; ss=0.f;
#pragma unroll
            for (int t=0;t<5;t++){
                const float v = siluf(t<4 ? c0[t] : c1[0]);
                X2o[t]=v; s+=v; ss+=v*v;
            }
            red4(s,ss);
            mn=s*0.05f; var=fmaxf(ss*0.05f-mn*mn,0.f);
            rs=__builtin_amdgcn_rsqf(var+1e-5f); mr=mn*rs;
            xnf = xpose(q, X2o[0]*rs-mr, X2o[1]*rs-mr, X2o[2]*rs-mr, X2o[3]*rs-mr, X2o[4]*rs-mr, bsl);
        };

        float c1s[5]={0,0,0,0,0};
        half8 h1f; { H8 z; z.u[0]=0;z.u[1]=0;z.u[2]=0;z.u[3]=0; h1f=z.v; }
        half8 xnfC; float X2C[5];
        PRE(0, xnfC, X2C);

        __syncthreads();                       // staging barrier (#1)

#pragma unroll 1
        for (int i=0;i<SEQ;i++){
            // issue LSTM1 mfmas for step i
            f32x4 ac[5];
#pragma unroll
            for (int t=0;t<5;t++){
                ac[t] = __builtin_amdgcn_mfma_f32_16x16x32_f16(Aih1[t], xnfC, Z, 0,0,0);
                ac[t] = __builtin_amdgcn_mfma_f32_16x16x32_f16(Ahh1[t], h1f, ac[t], 0,0,0);
            }
            // independent: preprocess step i+1 while mfmas are in flight
            half8 xnfN; float X2N[5];
            PRE((i<SEQ-1)? i+1 : SEQ-1, xnfN, X2N);

            // gates + residual + ln3
            float x3v[5], h1v[5], s=0.f, ss=0.f;
#pragma unroll
            for (int t=0;t<5;t++){
                const float h = gate_step(ac[t], c1s[t]);
                h1v[t]=h;
                const float xv = X2C[t]+h;
                x3v[t]=xv; s+=xv; ss+=xv*xv;
            }
            red4(s,ss);
            const float mn=s*0.05f, var=fmaxf(ss*0.05f-mn*mn,0.f);
            const float rs=__builtin_amdgcn_rsqf(var+1e-5f), mr=mn*rs;
            const half8 x3f = xpose(q, x3v[0]*rs-mr, x3v[1]*rs-mr, x3v[2]*rs-mr, x3v[3]*rs-mr, x3v[4]*rs-mr, bsl);
            h1f = xpose(q, h1v[0],h1v[1],h1v[2],h1v[3],h1v[4], 0.f);

            // hand off to wave B
            H8 fo; fo.v = x3f;
            sFr[i&1][lane] = make_uint4(fo.u[0],fo.u[1],fo.u[2],fo.u[3]);
            sPx[i&1][lane][0] = pkf(x3v[0],x3v[1]);
            sPx[i&1][lane][1] = pkf(x3v[2],x3v[3]);
            sPx[i&1][lane][2] = pkf(x3v[4],0.f);

            xnfC = xnfN;
#pragma unroll
            for (int t=0;t<5;t++) X2C[t]=X2N[t];

            __syncthreads();                   // slot i&1 published
        }
    } else {
        // ================= WAVE B: LSTM2 + post chain + heads (consumer) =================
        half8 Aa2[5], Ahh2[5];
#pragma unroll
        for (int t=0;t<5;t++){
            const int M = t*16 + col, u = M>>2, g = M&3, r = g*20+u;
            const float sc = (g==2)? -2.885390082f : -1.442695041f;
            H8 a,h;
#pragma unroll
            for (int j=0;j<8;j++){
                const int k = q*8+j;
                float va=0.f, vh=0.f;
                if (k<20){ va = wih2[r*20+k]*ln3g[k]*sc; vh = whh2[r*20+k]*sc; }
                else if (k==20){
                    float bb = bih2[r]+bhh2[r];
                    for (int kk=0;kk<20;kk++) bb += wih2[r*20+kk]*ln3b[kk];
                    va = bb*sc;
                }
                a.s[j]=f2h(va); h.s[j]=f2h(vh);
            }
            Aa2[t]=a.v; Ahh2[t]=h.v;
        }
        half8 A3[2], A4[2], A5[2];
#pragma unroll
        for (int tt=0;tt<2;tt++){
            const int u = uemap(tt, col);
            H8 a3,a4,a5;
#pragma unroll
            for (int j=0;j<8;j++){
                const int k = q*8+j;
                float v3=0.f,v4=0.f,v5=0.f;
                if (u>=0){
                    if (k<20){ v3=w3[u*20+k]*g4[k]; v4=w4[u*20+k]*g5[k]; v5=w5[u*20+k]*g6[k]; }
                    else if (k==20){ v3=b3[u]; v4=b4[u]; v5=b5[u]; }
                }
                a3.s[j]=f2h(v3); a4.s[j]=f2h(v4); a5.s[j]=f2h(v5);
            }
            A3[tt]=a3.v; A4[tt]=a4.v; A5[tt]=a5.v;
        }
        half8 Ahd;
        {
            const int m=col, hd=m>>2, j=m&3;
            const float* Wp = (hd==0)? wfw : (hd==1)? sfw : dfw;
            const float* Bp = (hd==0)? wfb : (hd==1)? sfb : dfb;
            const bool ok = (hd<3)&&(j<3);
            H8 a;
#pragma unroll
            for (int jj=0;jj<8;jj++){
                const int k = q*8+jj;
                float v=0.f;
                if (ok){ if (k<20) v=Wp[j*20+k]; else if (k==20) v=Bp[j]; }
                a.s[jj]=f2h(v);
            }
            Ahd=a.v;
        }
        const float bsl = (q==0)? 1.0f : 0.0f;
        float c2s[5]={0,0,0,0,0};
        half8 h2f; { H8 z; z.u[0]=0;z.u[1]=0;z.u[2]=0;z.u[3]=0; h2f=z.v; }

        __syncthreads();                       // staging barrier (#1)

#pragma unroll 1
        for (int i=0;i<SEQ;i++){
            __syncthreads();                   // wait for slot i&1
            const uint4 fr = sFr[i&1][lane];
            const uint p0 = sPx[i&1][lane][0];
            const uint p1 = sPx[i&1][lane][1];
            const uint p2 = sPx[i&1][lane][2];
            H8 fi; fi.u[0]=fr.x; fi.u[1]=fr.y; fi.u[2]=fr.z; fi.u[3]=fr.w;
            const half8 x3f = fi.v;

            f32x4 ac[5];
#pragma unroll
            for (int t=0;t<5;t++){
                ac[t] = __builtin_amdgcn_mfma_f32_16x16x32_f16(Aa2[t],  x3f, Z, 0,0,0);
                ac[t] = __builtin_amdgcn_mfma_f32_16x16x32_f16(Ahh2[t], h2f, ac[t], 0,0,0);
            }
            const float x3v[5] = { lo16(p0), hi16(p0), lo16(p1), hi16(p1), lo16(p2) };

            float h2v[5], x4[5], s=0.f, ss=0.f;
#pragma unroll
            for (int t=0;t<5;t++){
                h2v[t] = gate_step(ac[t], c2s[t]);
                x4[t]  = x3v[t] + h2v[t];
                s += x4[t]; ss += x4[t]*x4[t];
            }
            h2f = xpose(q, h2v[0],h2v[1],h2v[2],h2v[3],h2v[4], 0.f);

            // ---- post chain: ln4 -> lin3 -> ln5 -> lin4 -> +x4 -> ln6 -> lin5 -> heads
            red4(s,ss);
            float mn=s*0.05f, var=fmaxf(ss*0.05f-mn*mn,0.f);
            float rs=__builtin_amdgcn_rsqf(var+1e-5f), mr=mn*rs;
            half8 f4 = xpose(q, x4[0]*rs-mr, x4[1]*rs-mr, x4[2]*rs-mr, x4[3]*rs-mr, x4[4]*rs-mr, bsl);
            f32x4 c0 = __builtin_amdgcn_mfma_f32_16x16x32_f16(A3[0], f4, Z, 0,0,0);
            f32x4 c1 = __builtin_amdgcn_mfma_f32_16x16x32_f16(A3[1], f4, Z, 0,0,0);
            float hh[5]; s=0.f; ss=0.f;
#pragma unroll
            for (int t=0;t<5;t++){ hh[t]=siluf(t<4?c0[t]:c1[0]); s+=hh[t]; ss+=hh[t]*hh[t]; }
            red4(s,ss);
            mn=s*0.05f; var=fmaxf(ss*0.05f-mn*mn,0.f);
            rs=__builtin_amdgcn_rsqf(var+1e-5f); mr=mn*rs;
            half8 f5 = xpose(q, hh[0]*rs-mr, hh[1]*rs-mr, hh[2]*rs-mr, hh[3]*rs-mr, hh[4]*rs-mr, bsl);
            c0 = __builtin_amdgcn_mfma_f32_16x16x32_f16(A4[0], f5, Z, 0,0,0);
            c1 = __builtin_amdgcn_mfma_f32_16x16x32_f16(A4[1], f5, Z, 0,0,0);
            float xp[5]; s=0.f; ss=0.f;
#pragma unroll
            for (int t=0;t<5;t++){ xp[t]=x4[t]+siluf(t<4?c0[t]:c1[0]); s+=xp[t]; ss+=xp[t]*xp[t]; }
            red4(s,ss);
            mn=s*0.05f; var=fmaxf(ss*0.05f-mn*mn,0.f);
            rs=__builtin_amdgcn_rsqf(var+1e-5f); mr=mn*rs;
            half8 f6 = xpose(q, xp[0]*rs-mr, xp[1]*rs-mr, xp[2]*rs-mr, xp[3]*rs-mr, xp[4]*rs-mr, bsl);
            c0 = __builtin_amdgcn_mfma_f32_16x16x32_f16(A5[0], f6, Z, 0,0,0);
            c1 = __builtin_amdgcn_mfma_f32_16x16x32_f16(A5[1], f6, Z, 0,0,0);
            float xfv[5];
#pragma unroll
            for (int t=0;t<5;t++) xfv[t]=siluf(t<4?c0[t]:c1[0]);
            half8 fh = xpose(q, xfv[0],xfv[1],xfv[2],xfv[3],xfv[4], bsl);
            const f32x4 ch = __builtin_amdgcn_mfma_f32_16x16x32_f16(Ahd, fh, Z, 0,0,0);

            if (q<3){
                const size_t base = (size_t)q*T3 + ((size_t)i*8192 + (size_t)nt*16 + col)*3;
                if (q==0){
                    const float mx=fmaxf(ch[0],fmaxf(ch[1],ch[2]));
                    const float e0=__expf(ch[0]-mx), e1=__expf(ch[1]-mx), e2=__expf(ch[2]-mx);
                    const float inv=1.f/(e0+e1+e2);
                    out[base+0]=e0*inv; out[base+1]=e1*inv; out[base+2]=e2*inv;
                } else {
                    out[base+0]=__expf(fminf(fmaxf(ch[0],-25.f),25.f));
                    out[base+1]=__expf(fminf(fmaxf(ch[1],-25.f),25.f));
                    out[base+2]=__expf(fminf(fmaxf(ch[2],-25.f),25.f));
                }
            }
        }
    }
}

// ---------------------------------------------------------------- launch
extern "C" void kernel_launch(void* const* d_in, const int* in_sizes, int n_in,
                              void* d_out, int out_size, void* d_ws, size_t ws_size,
                              hipStream_t stream)
{
    (void)in_sizes; (void)n_in; (void)out_size; (void)d_ws; (void)ws_size;
    const float* xlni  = (const float*)d_in[0];
    const float* imean = (const float*)d_in[1];
    const float* istd  = (const float*)d_in[2];
    const float* l1w = (const float*)d_in[3];
    const float* l1b = (const float*)d_in[4];
    const float* g1  = (const float*)d_in[5];
    const float* l2w = (const float*)d_in[6];
    const float* l2b = (const float*)d_in[7];
    const float* g2  = (const float*)d_in[8];
    const float* wih1=(const float*)d_in[9];
    const float* whh1=(const float*)d_in[10];
    const float* bih1=(const float*)d_in[11];
    const float* bhh1=(const float*)d_in[12];
    const float* g3  =(const float*)d_in[13];
    const float* b3n =(const float*)d_in[14];
    const float* wih2=(const float*)d_in[15];
    const float* whh2=(const float*)d_in[16];
    const float* bih2=(const float*)d_in[17];
    const float* bhh2=(const float*)d_in[18];
    const float* g4  =(const float*)d_in[19];
    const float* l3w =(const float*)d_in[20];
    const float* l3b =(const float*)d_in[21];
    const float* g5  =(const float*)d_in[22];
    const float* l4w =(const float*)d_in[23];
    const float* l4b =(const float*)d_in[24];
    const float* g6  =(const float*)d_in[25];
    const float* l5w =(const float*)d_in[26];
    const float* l5b =(const float*)d_in[27];
    const float* wfw =(const float*)d_in[28];
    const float* wfb =(const float*)d_in[29];
    const float* sfw =(const float*)d_in[30];
    const float* sfb =(const float*)d_in[31];
    const float* dfw =(const float*)d_in[32];
    const float* dfb =(const float*)d_in[33];

    k_fused<<<NTL, 128, 0, stream>>>(
        xlni, imean, istd,
        l1w, l1b, g1, l2w, l2b, g2,
        wih1, whh1, bih1, bhh1, g3, b3n,
        wih2, whh2, bih2, bhh2,
        g4, l3w, l3b, g5, l4w, l4b, g6, l5w, l5b,
        wfw, wfb, sfw, sfb, dfw, dfb,
        (float*)d_out);
}

// Round 5
// 498.925 us; speedup vs baseline: 1.0084x; 1.0084x over previous
//
#include <hip/hip_runtime.h>
#include <hip/hip_fp16.h>

#define SEQ    128
#define NTL    512               /* n-tiles of 16 */
#define TOT    (SEQ*8192)        /* 1048576 */
#define T3     (TOT*3)
#define NWT    (SEQ*NTL)         /* 65536 (l,nt) wave-tiles */

typedef __attribute__((ext_vector_type(8))) _Float16 half8;
typedef __attribute__((ext_vector_type(4))) float    f32x4;
union H8 { half8 v; ushort s[8]; uint u[4]; };

__device__ __forceinline__ float siluf(float x){ return x/(1.f+__expf(-x)); }
__device__ __forceinline__ ushort f2h(float x){ _Float16 h=(_Float16)x; return __builtin_bit_cast(ushort,h); }
__device__ __forceinline__ float  h2fl(ushort u){ _Float16 h=__builtin_bit_cast(_Float16,u); return (float)h; }
__device__ __forceinline__ float  lo16(uint u){ return h2fl((ushort)(u&0xFFFFu)); }
__device__ __forceinline__ float  hi16(uint u){ return h2fl((ushort)(u>>16)); }
__device__ __forceinline__ uint   pkf(float a, float b){ auto r=__builtin_amdgcn_cvt_pkrtz(a,b); return __builtin_bit_cast(uint,r); }
__device__ __forceinline__ uint   shflx(uint v, int m){ return (uint)__shfl_xor((int)v, m, 64); }

// C-layout per-lane stream (v_t = value of unit 4t+q) -> MFMA B-fragment (k=unit, bias@k=20).
__device__ __forceinline__ half8 xpose(int q, float v0,float v1,float v2,float v3,float v4,float vb){
    const bool qb0=(q&1)!=0, qb1=(q&2)!=0;
    uint M0 = pkf(v0,v1), M1 = pkf(v2,v3), M2 = pkf(v4,vb);
    uint t0 = shflx(M1,16), t1 = shflx(M0,16), t3 = shflx(M2,16);
    uint A0 = qb0? t0:M0, A1 = qb0? M1:t1, A2 = qb0? 0u:M2, A3 = qb0? 0u:t3;
    uint s0 = shflx(A2,32), s1 = shflx(A3,32), s2 = shflx(A0,32), s3 = shflx(A1,32);
    uint R0 = qb1? s0:A0, R1 = qb1? s1:A1, R2 = qb1? A2:s2, R3 = qb1? A3:s3;
    H8 o;
    o.u[0]=(R0&0xFFFFu)|(R1<<16);
    o.u[1]=(R2&0xFFFFu)|(R3<<16);
    o.u[2]=(R0>>16)|(R1&0xFFFF0000u);
    o.u[3]=(R2>>16)|(R3&0xFFFF0000u);
    return o.v;
}

// gates pre-scaled by -1/ln2 (-2/ln2 for g row): pure exp2/rcp
__device__ __forceinline__ float gate_step(const f32x4 a, float& c){
    const float ei=__builtin_amdgcn_exp2f(a[0]);
    const float ef=__builtin_amdgcn_exp2f(a[1]);
    const float eg=__builtin_amdgcn_exp2f(a[2]);
    const float eo=__builtin_amdgcn_exp2f(a[3]);
    const float gi=__builtin_amdgcn_rcpf(1.f+ei);
    const float gf=__builtin_amdgcn_rcpf(1.f+ef);
    const float gg=2.f*__builtin_amdgcn_rcpf(1.f+eg)-1.f;
    const float go=__builtin_amdgcn_rcpf(1.f+eo);
    c = gf*c + gi*gg;
    const float ec=__builtin_amdgcn_exp2f(-2.885390082f*c);
    return go*(2.f*__builtin_amdgcn_rcpf(1.f+ec)-1.f);
}

__device__ __forceinline__ void red4(float& s, float& ss){
    s  += __shfl_xor(s,16,64);  s  += __shfl_xor(s,32,64);
    ss += __shfl_xor(ss,16,64); ss += __shfl_xor(ss,32,64);
}

// 20-row GEMV tile row->unit maps (verified in R4)
__device__ __forceinline__ int uemap(int tt, int m){
    if (tt==0) return 4*(m&3)+(m>>2);
    return ((m&3)==0) ? 16+(m>>2) : -1;
}

// ---------------------------------------------------------------- kernel 1: wave-tile PRE
// One wave per (l,nt): preprocessing -> lin1 -> ln1 -> lin2(MFMA) -> silu -> ln2.
// Emits xn B-fragment (WITHOUT gamma2 — folded into scan weights) and x2 packed C-layout.
__global__ __launch_bounds__(256) void k_pre(
    const float* __restrict__ xlni, const float* __restrict__ imean, const float* __restrict__ istd,
    const float* __restrict__ w1,  const float* __restrict__ b1,  const float* __restrict__ g1,
    const float* __restrict__ w2,  const float* __restrict__ b2,
    uint4* __restrict__ xnfrag, uint2* __restrict__ x2a, ushort* __restrict__ x2b)
{
    const int tid  = threadIdx.x;
    const int lane = tid & 63;
    const int col  = lane & 15, q = lane >> 4;
    const int wid  = blockIdx.x*4 + (tid>>6);
    const int l    = wid >> 9, nt = wid & 511;
    const f32x4 Z  = {0.f,0.f,0.f,0.f};

    // weights: lin1 rows for units 4t+q; lin2 as A-fragments (gamma1 folded)
    float wd[5], wu[5], ws0[5], ws1[5], ws2[5], ws3[5];
#pragma unroll
    for (int t=0;t<5;t++){
        const int u = 4*t+q;
        wd[t]=w1[u*6+0]; wu[t]=w1[u*6+1];
        ws0[t]=w1[u*6+2]+b1[u]; ws1[t]=w1[u*6+3]+b1[u];
        ws2[t]=w1[u*6+4]+b1[u]; ws3[t]=w1[u*6+5]+b1[u];
    }
    half8 Aw2[2];
#pragma unroll
    for (int tt=0;tt<2;tt++){
        const int u = uemap(tt, col);
        H8 a;
#pragma unroll
        for (int j=0;j<8;j++){
            const int k = q*8+j;
            float v=0.f;
            if (u>=0){ if (k<20) v = w2[u*20+k]*g1[k]; else if (k==20) v = b2[u]; }
            a.s[j]=f2h(v);
        }
        Aw2[tt]=a.v;
    }
    const float mu0=imean[0], mu1=imean[1];
    const float ri0=1.f/istd[0], ri1=1.f/istd[1];
    const float bsl = (q==0)? 1.0f : 0.0f;

    // input
    const size_t ib = ((size_t)l*8192 + (size_t)nt*16 + col)*3;
    const float d0 = xlni[ib+0], d1 = xlni[ib+1], rr = xlni[ib+2];
    const float xd = (__logf(1e-5f+d0)-mu0)*ri0;
    const float xu = (__logf(fminf(fmaxf(d1,100.f),60000.f))-mu1)*ri1;
    int r = (int)fmaxf(rr,1.f)-1; r = r<0?0:(r>3?3:r);

    float av[5], s=0.f, ss=0.f;
#pragma unroll
    for (int t=0;t<5;t++){
        const float wsel = (r==0)?ws0[t]:(r==1)?ws1[t]:(r==2)?ws2[t]:ws3[t];
        const float v = wd[t]*xd + wu[t]*xu + wsel;
        av[t]=siluf(v); s+=av[t]; ss+=av[t]*av[t];
    }
    red4(s,ss);
    float mn=s*0.05f, var=fmaxf(ss*0.05f-mn*mn,0.f);
    float rs=__builtin_amdgcn_rsqf(var+1e-5f); float mr=mn*rs;
    const half8 yf = xpose(q, av[0]*rs-mr, av[1]*rs-mr, av[2]*rs-mr, av[3]*rs-mr, av[4]*rs-mr, bsl);
    const f32x4 c0 = __builtin_amdgcn_mfma_f32_16x16x32_f16(Aw2[0], yf, Z, 0,0,0);
    const f32x4 c1 = __builtin_amdgcn_mfma_f32_16x16x32_f16(Aw2[1], yf, Z, 0,0,0);
    float X2[5]; s=0.f; ss=0.f;
#pragma unroll
    for (int t=0;t<5;t++){
        const float v = siluf(t<4 ? c0[t] : c1[0]);
        X2[t]=v; s+=v; ss+=v*v;
    }
    red4(s,ss);
    mn=s*0.05f; var=fmaxf(ss*0.05f-mn*mn,0.f);
    rs=__builtin_amdgcn_rsqf(var+1e-5f); mr=mn*rs;
    const half8 xnf = xpose(q, X2[0]*rs-mr, X2[1]*rs-mr, X2[2]*rs-mr, X2[3]*rs-mr, X2[4]*rs-mr, bsl);

    H8 fo; fo.v = xnf;
    xnfrag[(size_t)wid*64 + lane] = make_uint4(fo.u[0],fo.u[1],fo.u[2],fo.u[3]);
    x2a[(size_t)wid*64 + lane]   = make_uint2(pkf(X2[0],X2[1]), pkf(X2[2],X2[3]));
    x2b[(size_t)wid*64 + lane]   = f2h(X2[4]);
}

// ---------------------------------------------------------------- kernel 2: fused double-LSTM scan (R3-proven)
// gamma2 folded into Aih1 (PRE emits un-scaled ln2 output).
__global__ __launch_bounds__(64) void k_scan(
    const uint4* __restrict__ xnfrag, uint2* __restrict__ x4a, ushort* __restrict__ x4b,
    const float* __restrict__ g2,
    const float* __restrict__ wih1, const float* __restrict__ whh1,
    const float* __restrict__ bih1, const float* __restrict__ bhh1,
    const float* __restrict__ ln3g, const float* __restrict__ ln3b,
    const float* __restrict__ wih2, const float* __restrict__ whh2,
    const float* __restrict__ bih2, const float* __restrict__ bhh2)
{
    const int lane = threadIdx.x & 63;
    const int col = lane & 15, q = lane >> 4;
    const int nt = blockIdx.x;

    half8 Aih1[5], Ahh1[5], Aa2[5], Ahh2[5];
#pragma unroll
    for (int t=0;t<5;t++){
        const int M = t*16 + col, u = M>>2, g = M&3, r = g*20+u;
        const float sc = (g==2)? -2.885390082f : -1.442695041f;
        H8 a0,a1,a2,a3;
#pragma unroll
        for (int j=0;j<8;j++){
            const int k = q*8+j;
            float vih1=0.f, vhh1=0.f, va2=0.f, vhh2=0.f;
            if (k<20){
                vih1 = wih1[r*20+k]*g2[k]*sc;      // gamma2 folded here (PRE output un-scaled)
                vhh1 = whh1[r*20+k]*sc;
                va2  = wih2[r*20+k]*ln3g[k]*sc;
                vhh2 = whh2[r*20+k]*sc;
            } else if (k==20){
                vih1 = (bih1[r]+bhh1[r])*sc;
                float b2 = bih2[r]+bhh2[r];
                for (int kk=0;kk<20;kk++) b2 += wih2[r*20+kk]*ln3b[kk];
                va2 = b2*sc;
            }
            a0.s[j]=f2h(vih1); a1.s[j]=f2h(vhh1); a2.s[j]=f2h(va2); a3.s[j]=f2h(vhh2);
        }
        Aih1[t]=a0.v; Ahh1[t]=a1.v; Aa2[t]=a2.v; Ahh2[t]=a3.v;
    }

    const float bsl = (q==0)? 1.0f : 0.0f;
    const size_t TSTR = (size_t)NTL*64;
    const uint4* xf   = xnfrag + (size_t)nt*64 + lane;
    uint2*       x4ap = x4a    + (size_t)nt*64 + lane;
    ushort*      x4bp = x4b    + (size_t)nt*64 + lane;

    float c1[5]={0,0,0,0,0}, c2[5]={0,0,0,0,0};
    const f32x4 Z = {0.f,0.f,0.f,0.f};
    f32x4 ac1[5], ac2[5];
    float x3v[5], h1v[5], h2v[5];

    // ---- preamble: LSTM1 step 0, issue ac2(0), ac1(1)
    uint4 xn0 = xf[0];
    uint2 w0  = x4ap[0]; ushort wb0 = x4bp[0];
#pragma unroll
    for (int t=0;t<5;t++) ac1[t] = __builtin_amdgcn_mfma_f32_16x16x32_f16(Aih1[t], __builtin_bit_cast(half8,xn0), Z, 0,0,0);
    {
        float x2r[5] = { lo16(w0.x), hi16(w0.x), lo16(w0.y), hi16(w0.y), h2fl(wb0) };
        float s=0.f, ss=0.f;
#pragma unroll
        for (int t=0;t<5;t++){
            const float h = gate_step(ac1[t], c1[t]);
            h1v[t]=h;
            const float xv = x2r[t]+h;
            x3v[t]=xv; s+=xv; ss+=xv*xv;
        }
        red4(s,ss);
        const float mn=s*0.05f; float var=fmaxf(ss*0.05f-mn*mn,0.f);
        const float rs=__builtin_amdgcn_rsqf(var+1e-5f), mr=mn*rs;
        half8 x3f = xpose(q, x3v[0]*rs-mr, x3v[1]*rs-mr, x3v[2]*rs-mr, x3v[3]*rs-mr, x3v[4]*rs-mr, bsl);
        half8 h1f = xpose(q, h1v[0],h1v[1],h1v[2],h1v[3],h1v[4], 0.f);
#pragma unroll
        for (int t=0;t<5;t++) ac2[t] = __builtin_amdgcn_mfma_f32_16x16x32_f16(Aa2[t], x3f, Z, 0,0,0);
        uint4 xn1 = xf[TSTR];
#pragma unroll
        for (int t=0;t<5;t++){
            ac1[t] = __builtin_amdgcn_mfma_f32_16x16x32_f16(Aih1[t], __builtin_bit_cast(half8,xn1), Z, 0,0,0);
            ac1[t] = __builtin_amdgcn_mfma_f32_16x16x32_f16(Ahh1[t], h1f, ac1[t], 0,0,0);
        }
    }
    half8 h2f; { H8 z; z.u[0]=0;z.u[1]=0;z.u[2]=0;z.u[3]=0; h2f=z.v; }
    uint4 xnCur = xf[2*TSTR],  xnNxt = xf[3*TSTR];
    uint2 x2CurA = x4ap[1*TSTR]; ushort x2CurB = x4bp[1*TSTR];
    uint2 x2NxtA = x4ap[2*TSTR]; ushort x2NxtB = x4bp[2*TSTR];

#pragma unroll 2
    for (int l=0;l<127;l++){
        const size_t lpx = (size_t)((l+4<128)? l+4:127) * TSTR;
        const size_t lp2 = (size_t)((l+3<128)? l+3:127) * TSTR;
        uint4  xnNew  = xf[lpx];
        uint2  x2NewA = x4ap[lp2]; ushort x2NewB = x4bp[lp2];

        // ---- LSTM2 step l
#pragma unroll
        for (int t=0;t<5;t++) h2v[t] = gate_step(ac2[t], c2[t]);
        {
            const float o0=x3v[0]+h2v[0], o1=x3v[1]+h2v[1], o2=x3v[2]+h2v[2], o3=x3v[3]+h2v[3], o4=x3v[4]+h2v[4];
            x4ap[(size_t)l*TSTR] = make_uint2(pkf(o0,o1), pkf(o2,o3));
            x4bp[(size_t)l*TSTR] = f2h(o4);
        }
        half8 h2fn = xpose(q, h2v[0],h2v[1],h2v[2],h2v[3],h2v[4], 0.f);

        // ---- LSTM1 step l+1
        float x2r[5] = { lo16(x2CurA.x), hi16(x2CurA.x), lo16(x2CurA.y), hi16(x2CurA.y), h2fl(x2CurB) };
        float s=0.f, ss=0.f;
#pragma unroll
        for (int t=0;t<5;t++){
            const float h = gate_step(ac1[t], c1[t]);
            h1v[t]=h;
            const float xv = x2r[t]+h;
            x3v[t]=xv; s+=xv; ss+=xv*xv;
        }
        half8 h1f = xpose(q, h1v[0],h1v[1],h1v[2],h1v[3],h1v[4], 0.f);
        red4(s,ss);
        const float mn=s*0.05f; float var=fmaxf(ss*0.05f-mn*mn,0.f);
        const float rs=__builtin_amdgcn_rsqf(var+1e-5f), mr=mn*rs;
        half8 x3f = xpose(q, x3v[0]*rs-mr, x3v[1]*rs-mr, x3v[2]*rs-mr, x3v[3]*rs-mr, x3v[4]*rs-mr, bsl);
        h2f = h2fn;

        // ---- issue ac2(l+1), ac1(l+2)
#pragma unroll
        for (int t=0;t<5;t++){
            ac2[t] = __builtin_amdgcn_mfma_f32_16x16x32_f16(Aa2[t],  x3f, Z, 0,0,0);
            ac2[t] = __builtin_amdgcn_mfma_f32_16x16x32_f16(Ahh2[t], h2f, ac2[t], 0,0,0);
        }
        const half8 xnf = __builtin_bit_cast(half8, xnCur);
#pragma unroll
        for (int t=0;t<5;t++){
            ac1[t] = __builtin_amdgcn_mfma_f32_16x16x32_f16(Aih1[t], xnf, Z, 0,0,0);
            ac1[t] = __builtin_amdgcn_mfma_f32_16x16x32_f16(Ahh1[t], h1f, ac1[t], 0,0,0);
        }
        xnCur = xnNxt;  xnNxt = xnNew;
        x2CurA = x2NxtA; x2CurB = x2NxtB;
        x2NxtA = x2NewA; x2NxtB = x2NewB;
    }
    // ---- epilogue: LSTM2 step 127
#pragma unroll
    for (int t=0;t<5;t++) h2v[t] = gate_step(ac2[t], c2[t]);
    {
        const float o0=x3v[0]+h2v[0], o1=x3v[1]+h2v[1], o2=x3v[2]+h2v[2], o3=x3v[3]+h2v[3], o4=x3v[4]+h2v[4];
        x4ap[(size_t)127*TSTR] = make_uint2(pkf(o0,o1), pkf(o2,o3));
        x4bp[(size_t)127*TSTR] = f2h(o4);
    }
}

// ---------------------------------------------------------------- kernel 3: wave-tile POST
// One wave per (l,nt): ln4 -> lin3 -> ln5 -> lin4 -> +x4 -> ln6 -> lin5 -> 3 heads.
__global__ __launch_bounds__(256) void k_post(
    const uint2* __restrict__ x4a, const ushort* __restrict__ x4b,
    const float* __restrict__ g4, const float* __restrict__ w3, const float* __restrict__ b3,
    const float* __restrict__ g5, const float* __restrict__ w4, const float* __restrict__ b4,
    const float* __restrict__ g6, const float* __restrict__ w5, const float* __restrict__ b5,
    const float* __restrict__ wfw, const float* __restrict__ wfb,
    const float* __restrict__ sfw, const float* __restrict__ sfb,
    const float* __restrict__ dfw, const float* __restrict__ dfb,
    float* __restrict__ out)
{
    const int tid  = threadIdx.x;
    const int lane = tid & 63;
    const int col  = lane & 15, q = lane >> 4;
    const int wid  = blockIdx.x*4 + (tid>>6);
    const int l    = wid >> 9, nt = wid & 511;
    const f32x4 Z  = {0.f,0.f,0.f,0.f};

    half8 A3[2], A4[2], A5[2];
#pragma unroll
    for (int tt=0;tt<2;tt++){
        const int u = uemap(tt, col);
        H8 a3,a4,a5;
#pragma unroll
        for (int j=0;j<8;j++){
            const int k = q*8+j;
            float v3=0.f,v4=0.f,v5=0.f;
            if (u>=0){
                if (k<20){ v3=w3[u*20+k]*g4[k]; v4=w4[u*20+k]*g5[k]; v5=w5[u*20+k]*g6[k]; }
                else if (k==20){ v3=b3[u]; v4=b4[u]; v5=b5[u]; }
            }
            a3.s[j]=f2h(v3); a4.s[j]=f2h(v4); a5.s[j]=f2h(v5);
        }
        A3[tt]=a3.v; A4[tt]=a4.v; A5[tt]=a5.v;
    }
    half8 Ahd;
    {
        const int m=col, hd=m>>2, j=m&3;
        const float* Wp = (hd==0)? wfw : (hd==1)? sfw : dfw;
        const float* Bp = (hd==0)? wfb : (hd==1)? sfb : dfb;
        const bool ok = (hd<3)&&(j<3);
        H8 a;
#pragma unroll
        for (int jj=0;jj<8;jj++){
            const int k = q*8+jj;
            float v=0.f;
            if (ok){ if (k<20) v=Wp[j*20+k]; else if (k==20) v=Bp[j]; }
            a.s[jj]=f2h(v);
        }
        Ahd=a.v;
    }
    const float bsl = (q==0)? 1.0f : 0.0f;

    const uint2  pa = x4a[(size_t)wid*64 + lane];
    const ushort pb = x4b[(size_t)wid*64 + lane];
    float x4[5] = { lo16(pa.x), hi16(pa.x), lo16(pa.y), hi16(pa.y), h2fl(pb) };

    float s=0.f, ss=0.f;
#pragma unroll
    for (int t=0;t<5;t++){ s+=x4[t]; ss+=x4[t]*x4[t]; }
    red4(s,ss);
    float mn=s*0.05f, var=fmaxf(ss*0.05f-mn*mn,0.f);
    float rs=__builtin_amdgcn_rsqf(var+1e-5f), mr=mn*rs;
    half8 f4 = xpose(q, x4[0]*rs-mr, x4[1]*rs-mr, x4[2]*rs-mr, x4[3]*rs-mr, x4[4]*rs-mr, bsl);
    f32x4 c0 = __builtin_amdgcn_mfma_f32_16x16x32_f16(A3[0], f4, Z, 0,0,0);
    f32x4 c1 = __builtin_amdgcn_mfma_f32_16x16x32_f16(A3[1], f4, Z, 0,0,0);
    float hh[5]; s=0.f; ss=0.f;
#pragma unroll
    for (int t=0;t<5;t++){ hh[t]=siluf(t<4?c0[t]:c1[0]); s+=hh[t]; ss+=hh[t]*hh[t]; }
    red4(s,ss);
    mn=s*0.05f; var=fmaxf(ss*0.05f-mn*mn,0.f);
    rs=__builtin_amdgcn_rsqf(var+1e-5f); mr=mn*rs;
    half8 f5 = xpose(q, hh[0]*rs-mr, hh[1]*rs-mr, hh[2]*rs-mr, hh[3]*rs-mr, hh[4]*rs-mr, bsl);
    c0 = __builtin_amdgcn_mfma_f32_16x16x32_f16(A4[0], f5, Z, 0,0,0);
    c1 = __builtin_amdgcn_mfma_f32_16x16x32_f16(A4[1], f5, Z, 0,0,0);
    float xp[5]; s=0.f; ss=0.f;
#pragma unroll
    for (int t=0;t<5;t++){ xp[t]=x4[t]+siluf(t<4?c0[t]:c1[0]); s+=xp[t]; ss+=xp[t]*xp[t]; }
    red4(s,ss);
    mn=s*0.05f; var=fmaxf(ss*0.05f-mn*mn,0.f);
    rs=__builtin_amdgcn_rsqf(var+1e-5f); mr=mn*rs;
    half8 f6 = xpose(q, xp[0]*rs-mr, xp[1]*rs-mr, xp[2]*rs-mr, xp[3]*rs-mr, xp[4]*rs-mr, bsl);
    c0 = __builtin_amdgcn_mfma_f32_16x16x32_f16(A5[0], f6, Z, 0,0,0);
    c1 = __builtin_amdgcn_mfma_f32_16x16x32_f16(A5[1], f6, Z, 0,0,0);
    float xfv[5];
#pragma unroll
    for (int t=0;t<5;t++) xfv[t]=siluf(t<4?c0[t]:c1[0]);
    half8 fh = xpose(q, xfv[0],xfv[1],xfv[2],xfv[3],xfv[4], bsl);
    const f32x4 ch = __builtin_amdgcn_mfma_f32_16x16x32_f16(Ahd, fh, Z, 0,0,0);

    if (q<3){
        const size_t base = (size_t)q*T3 + ((size_t)l*8192 + (size_t)nt*16 + col)*3;
        if (q==0){
            const float mx=fmaxf(ch[0],fmaxf(ch[1],ch[2]));
            const float e0=__expf(ch[0]-mx), e1=__expf(ch[1]-mx), e2=__expf(ch[2]-mx);
            const float inv=1.f/(e0+e1+e2);
            out[base+0]=e0*inv; out[base+1]=e1*inv; out[base+2]=e2*inv;
        } else {
            out[base+0]=__expf(fminf(fmaxf(ch[0],-25.f),25.f));
            out[base+1]=__expf(fminf(fmaxf(ch[1],-25.f),25.f));
            out[base+2]=__expf(fminf(fmaxf(ch[2],-25.f),25.f));
        }
    }
}

// ---------------------------------------------------------------- launch
extern "C" void kernel_launch(void* const* d_in, const int* in_sizes, int n_in,
                              void* d_out, int out_size, void* d_ws, size_t ws_size,
                              hipStream_t stream)
{
    (void)in_sizes; (void)n_in; (void)out_size; (void)ws_size;
    const float* xlni  = (const float*)d_in[0];
    const float* imean = (const float*)d_in[1];
    const float* istd  = (const float*)d_in[2];
    const float* l1w = (const float*)d_in[3];
    const float* l1b = (const float*)d_in[4];
    const float* g1  = (const float*)d_in[5];
    const float* l2w = (const float*)d_in[6];
    const float* l2b = (const float*)d_in[7];
    const float* g2  = (const float*)d_in[8];
    const float* wih1=(const float*)d_in[9];
    const float* whh1=(const float*)d_in[10];
    const float* bih1=(const float*)d_in[11];
    const float* bhh1=(const float*)d_in[12];
    const float* g3  =(const float*)d_in[13];
    const float* b3n =(const float*)d_in[14];
    const float* wih2=(const float*)d_in[15];
    const float* whh2=(const float*)d_in[16];
    const float* bih2=(const float*)d_in[17];
    const float* bhh2=(const float*)d_in[18];
    const float* g4  =(const float*)d_in[19];
    const float* l3w =(const float*)d_in[20];
    const float* l3b =(const float*)d_in[21];
    const float* g5  =(const float*)d_in[22];
    const float* l4w =(const float*)d_in[23];
    const float* l4b =(const float*)d_in[24];
    const float* g6  =(const float*)d_in[25];
    const float* l5w =(const float*)d_in[26];
    const float* l5b =(const float*)d_in[27];
    const float* wfw =(const float*)d_in[28];
    const float* wfb =(const float*)d_in[29];
    const float* sfw =(const float*)d_in[30];
    const float* sfb =(const float*)d_in[31];
    const float* dfw =(const float*)d_in[32];
    const float* dfb =(const float*)d_in[33];

    uint4* xnfrag = (uint4*)d_ws;                                  // NWT*64*16B = 64 MiB
    uint2* x4a    = (uint2*)((char*)d_ws + 67108864ull);           // NWT*64*8B  = 32 MiB (x2 then x4)
    ushort* x4b   = (ushort*)((char*)d_ws + 100663296ull);         // NWT*64*2B  =  8 MiB

    k_pre <<<NWT/4, 256, 0, stream>>>(xlni, imean, istd, l1w, l1b, g1, l2w, l2b,
                                      xnfrag, x4a, x4b);
    k_scan<<<NTL, 64, 0, stream>>>(xnfrag, x4a, x4b, g2,
                                   wih1, whh1, bih1, bhh1, g3, b3n,
                                   wih2, whh2, bih2, bhh2);
    k_post<<<NWT/4, 256, 0, stream>>>(x4a, x4b, g4, l3w, l3b, g5, l4w, l4b, g6, l5w, l5b,
                                      wfw, wfb, sfw, sfb, dfw, dfb, (float*)d_out);
}

// Round 6
// 400.973 us; speedup vs baseline: 1.2547x; 1.2443x over previous
//
#include <hip/hip_runtime.h>
#include <hip/hip_fp16.h>

#define SEQ    128
#define NTL    512               /* n-tiles of 16 */
#define TOT    (SEQ*8192)        /* 1048576 */
#define T3     (TOT*3)
#define NWT    (SEQ*NTL)         /* 65536 (l,nt) wave-tiles */
#define TPW    8                 /* tiles per wave in pre/post */

typedef __attribute__((ext_vector_type(8))) _Float16 half8;
typedef __attribute__((ext_vector_type(4))) float    f32x4;
union H8 { half8 v; ushort s[8]; uint u[4]; };

__device__ __forceinline__ float siluf(float x){ return x/(1.f+__expf(-x)); }
__device__ __forceinline__ ushort f2h(float x){ _Float16 h=(_Float16)x; return __builtin_bit_cast(ushort,h); }
__device__ __forceinline__ float  h2fl(ushort u){ _Float16 h=__builtin_bit_cast(_Float16,u); return (float)h; }
__device__ __forceinline__ float  lo16(uint u){ return h2fl((ushort)(u&0xFFFFu)); }
__device__ __forceinline__ float  hi16(uint u){ return h2fl((ushort)(u>>16)); }
__device__ __forceinline__ uint   pkf(float a, float b){ auto r=__builtin_amdgcn_cvt_pkrtz(a,b); return __builtin_bit_cast(uint,r); }

// K-slot permutation: k-slot 8g+j holds unit 4j+g (j<5); bias at k-slot 5 (g=0,j=5); rest zero.
// With gate rows interleaved M=4u+g, the MFMA C-layout (lane q,col; reg t -> unit 4t+q)
// IS the B-layout for the next step: pack per-lane, no cross-lane transpose.
__device__ __forceinline__ half8 packB(int q, float v0,float v1,float v2,float v3,float v4,float vb){
    H8 o;
    o.u[0]=pkf(v0,v1);
    o.u[1]=pkf(v2,v3);
    o.u[2]=pkf(v4, (q==0)? vb : 0.f);
    o.u[3]=0u;
    return o.v;
}

// gates pre-scaled by -1/ln2 (-2/ln2 for g row): pure exp2/rcp
__device__ __forceinline__ float gate_step(const f32x4 a, float& c){
    const float ei=__builtin_amdgcn_exp2f(a[0]);
    const float ef=__builtin_amdgcn_exp2f(a[1]);
    const float eg=__builtin_amdgcn_exp2f(a[2]);
    const float eo=__builtin_amdgcn_exp2f(a[3]);
    const float gi=__builtin_amdgcn_rcpf(1.f+ei);
    const float gf=__builtin_amdgcn_rcpf(1.f+ef);
    const float gg=2.f*__builtin_amdgcn_rcpf(1.f+eg)-1.f;
    const float go=__builtin_amdgcn_rcpf(1.f+eo);
    c = gf*c + gi*gg;
    const float ec=__builtin_amdgcn_exp2f(-2.885390082f*c);
    return go*(2.f*__builtin_amdgcn_rcpf(1.f+ec)-1.f);
}

__device__ __forceinline__ void red4(float& s, float& ss){
    s  += __shfl_xor(s,16,64);  s  += __shfl_xor(s,32,64);
    ss += __shfl_xor(ss,16,64); ss += __shfl_xor(ss,32,64);
}

// 20-row GEMV tile row->unit maps (C reg r of tile0 = unit 4r+q; tile1 reg0 = unit 16+q)
__device__ __forceinline__ int uemap(int tt, int m){
    if (tt==0) return 4*(m&3)+(m>>2);
    return ((m&3)==0) ? 16+(m>>2) : -1;
}

// ---------------------------------------------------------------- kernel 1: PRE (8 tiles/wave)
__global__ __launch_bounds__(256) void k_pre(
    const float* __restrict__ xlni, const float* __restrict__ imean, const float* __restrict__ istd,
    const float* __restrict__ w1,  const float* __restrict__ b1,  const float* __restrict__ g1,
    const float* __restrict__ w2,  const float* __restrict__ b2,
    uint4* __restrict__ xnfrag, uint2* __restrict__ x2a, ushort* __restrict__ x2b)
{
    const int tid  = threadIdx.x;
    const int lane = tid & 63;
    const int col  = lane & 15, q = lane >> 4;
    const int wv   = blockIdx.x*4 + (tid>>6);
    const f32x4 Z  = {0.f,0.f,0.f,0.f};

    // lin1 rows for units 4t+q
    float wd[5], wu[5], ws0[5], ws1[5], ws2[5], ws3[5];
#pragma unroll
    for (int t=0;t<5;t++){
        const int u = 4*t+q;
        wd[t]=w1[u*6+0]; wu[t]=w1[u*6+1];
        ws0[t]=w1[u*6+2]+b1[u]; ws1[t]=w1[u*6+3]+b1[u];
        ws2[t]=w1[u*6+4]+b1[u]; ws3[t]=w1[u*6+5]+b1[u];
    }
    // lin2 A-fragments, gamma1 folded, permuted K-slots
    half8 Aw2[2];
#pragma unroll
    for (int tt=0;tt<2;tt++){
        const int u = uemap(tt, col);
        H8 a;
#pragma unroll
        for (int j=0;j<8;j++){
            float v=0.f;
            if (u>=0){
                if (j<5){ const int un=4*j+q; v = w2[u*20+un]*g1[un]; }
                else if (j==5 && q==0) v = b2[u];
            }
            a.s[j]=f2h(v);
        }
        Aw2[tt]=a.v;
    }
    const float mu0=imean[0], mu1=imean[1];
    const float ri0=1.f/istd[0], ri1=1.f/istd[1];

#pragma unroll 1
    for (int i=0;i<TPW;i++){
        const int tile = wv*TPW + i;
        const int l = tile>>9, nt = tile&511;
        const size_t ib = ((size_t)l*8192 + (size_t)nt*16 + col)*3;
        const float d0 = xlni[ib+0], d1 = xlni[ib+1], rr = xlni[ib+2];
        const float xd = (__logf(1e-5f+d0)-mu0)*ri0;
        const float xu = (__logf(fminf(fmaxf(d1,100.f),60000.f))-mu1)*ri1;
        int r = (int)fmaxf(rr,1.f)-1; r = r<0?0:(r>3?3:r);

        float av[5], s=0.f, ss=0.f;
#pragma unroll
        for (int t=0;t<5;t++){
            const float wsel = (r==0)?ws0[t]:(r==1)?ws1[t]:(r==2)?ws2[t]:ws3[t];
            const float v = wd[t]*xd + wu[t]*xu + wsel;
            av[t]=siluf(v); s+=av[t]; ss+=av[t]*av[t];
        }
        red4(s,ss);
        float mn=s*0.05f, var=fmaxf(ss*0.05f-mn*mn,0.f);
        float rs=__builtin_amdgcn_rsqf(var+1e-5f); float mr=mn*rs;
        const half8 yf = packB(q, av[0]*rs-mr, av[1]*rs-mr, av[2]*rs-mr, av[3]*rs-mr, av[4]*rs-mr, 1.0f);
        const f32x4 c0 = __builtin_amdgcn_mfma_f32_16x16x32_f16(Aw2[0], yf, Z, 0,0,0);
        const f32x4 c1 = __builtin_amdgcn_mfma_f32_16x16x32_f16(Aw2[1], yf, Z, 0,0,0);
        float X2[5]; s=0.f; ss=0.f;
#pragma unroll
        for (int t=0;t<5;t++){
            const float v = siluf(t<4 ? c0[t] : c1[0]);
            X2[t]=v; s+=v; ss+=v*v;
        }
        red4(s,ss);
        mn=s*0.05f; var=fmaxf(ss*0.05f-mn*mn,0.f);
        rs=__builtin_amdgcn_rsqf(var+1e-5f); mr=mn*rs;
        const half8 xnf = packB(q, X2[0]*rs-mr, X2[1]*rs-mr, X2[2]*rs-mr, X2[3]*rs-mr, X2[4]*rs-mr, 1.0f);

        H8 fo; fo.v = xnf;
        xnfrag[(size_t)tile*64 + lane] = make_uint4(fo.u[0],fo.u[1],fo.u[2],fo.u[3]);
        x2a[(size_t)tile*64 + lane]   = make_uint2(pkf(X2[0],X2[1]), pkf(X2[2],X2[3]));
        x2b[(size_t)tile*64 + lane]   = f2h(X2[4]);
    }
}

// ---------------------------------------------------------------- kernel 2: fused double-LSTM scan
__global__ __launch_bounds__(64) void k_scan(
    const uint4* __restrict__ xnfrag, uint2* __restrict__ x4a, ushort* __restrict__ x4b,
    const float* __restrict__ g2,
    const float* __restrict__ wih1, const float* __restrict__ whh1,
    const float* __restrict__ bih1, const float* __restrict__ bhh1,
    const float* __restrict__ ln3g, const float* __restrict__ ln3b,
    const float* __restrict__ wih2, const float* __restrict__ whh2,
    const float* __restrict__ bih2, const float* __restrict__ bhh2)
{
    const int lane = threadIdx.x & 63;
    const int col = lane & 15, q = lane >> 4;
    const int nt = blockIdx.x;

    half8 Aih1[5], Ahh1[5], Aa2[5], Ahh2[5];
#pragma unroll
    for (int t=0;t<5;t++){
        const int M = t*16 + col, u = M>>2, g = M&3, r = g*20+u;
        const float sc = (g==2)? -2.885390082f : -1.442695041f;
        H8 a0,a1,a2,a3;
#pragma unroll
        for (int j=0;j<8;j++){
            float vih1=0.f, vhh1=0.f, va2=0.f, vhh2=0.f;
            if (j<5){
                const int un = 4*j+q;
                vih1 = wih1[r*20+un]*g2[un]*sc;
                vhh1 = whh1[r*20+un]*sc;
                va2  = wih2[r*20+un]*ln3g[un]*sc;
                vhh2 = whh2[r*20+un]*sc;
            } else if (j==5 && q==0){
                vih1 = (bih1[r]+bhh1[r])*sc;
                float b2 = bih2[r]+bhh2[r];
                for (int kk=0;kk<20;kk++) b2 += wih2[r*20+kk]*ln3b[kk];
                va2 = b2*sc;
            }
            a0.s[j]=f2h(vih1); a1.s[j]=f2h(vhh1); a2.s[j]=f2h(va2); a3.s[j]=f2h(vhh2);
        }
        Aih1[t]=a0.v; Ahh1[t]=a1.v; Aa2[t]=a2.v; Ahh2[t]=a3.v;
    }

    const size_t TSTR = (size_t)NTL*64;
    const uint4* xf   = xnfrag + (size_t)nt*64 + lane;
    uint2*       x4ap = x4a    + (size_t)nt*64 + lane;
    ushort*      x4bp = x4b    + (size_t)nt*64 + lane;

    float c1[5]={0,0,0,0,0}, c2[5]={0,0,0,0,0};
    const f32x4 Z = {0.f,0.f,0.f,0.f};
    f32x4 ac1[5], ac2[5];
    float x3v[5], h1v[5], h2v[5];

    // ---- preamble: LSTM1 step 0, issue ac2(0), ac1(1)
    uint4 xn0 = xf[0];
    uint2 w0  = x4ap[0]; ushort wb0 = x4bp[0];
#pragma unroll
    for (int t=0;t<5;t++) ac1[t] = __builtin_amdgcn_mfma_f32_16x16x32_f16(Aih1[t], __builtin_bit_cast(half8,xn0), Z, 0,0,0);
    {
        float x2r[5] = { lo16(w0.x), hi16(w0.x), lo16(w0.y), hi16(w0.y), h2fl(wb0) };
        float s=0.f, ss=0.f;
#pragma unroll
        for (int t=0;t<5;t++){
            const float h = gate_step(ac1[t], c1[t]);
            h1v[t]=h;
            const float xv = x2r[t]+h;
            x3v[t]=xv; s+=xv; ss+=xv*xv;
        }
        red4(s,ss);
        const float mn=s*0.05f; float var=fmaxf(ss*0.05f-mn*mn,0.f);
        const float rs=__builtin_amdgcn_rsqf(var+1e-5f), mr=mn*rs;
        half8 x3f = packB(q, x3v[0]*rs-mr, x3v[1]*rs-mr, x3v[2]*rs-mr, x3v[3]*rs-mr, x3v[4]*rs-mr, 1.0f);
        half8 h1f = packB(q, h1v[0],h1v[1],h1v[2],h1v[3],h1v[4], 0.f);
#pragma unroll
        for (int t=0;t<5;t++) ac2[t] = __builtin_amdgcn_mfma_f32_16x16x32_f16(Aa2[t], x3f, Z, 0,0,0);
        uint4 xn1 = xf[TSTR];
#pragma unroll
        for (int t=0;t<5;t++){
            ac1[t] = __builtin_amdgcn_mfma_f32_16x16x32_f16(Aih1[t], __builtin_bit_cast(half8,xn1), Z, 0,0,0);
            ac1[t] = __builtin_amdgcn_mfma_f32_16x16x32_f16(Ahh1[t], h1f, ac1[t], 0,0,0);
        }
    }
    half8 h2f; { H8 z; z.u[0]=0;z.u[1]=0;z.u[2]=0;z.u[3]=0; h2f=z.v; }
    uint4 xnCur = xf[2*TSTR],  xnNxt = xf[3*TSTR];
    uint2 x2CurA = x4ap[1*TSTR]; ushort x2CurB = x4bp[1*TSTR];
    uint2 x2NxtA = x4ap[2*TSTR]; ushort x2NxtB = x4bp[2*TSTR];

#pragma unroll 2
    for (int l=0;l<127;l++){
        const size_t lpx = (size_t)((l+4<128)? l+4:127) * TSTR;
        const size_t lp2 = (size_t)((l+3<128)? l+3:127) * TSTR;
        uint4  xnNew  = xf[lpx];
        uint2  x2NewA = x4ap[lp2]; ushort x2NewB = x4bp[lp2];

        // ---- LSTM2 step l
#pragma unroll
        for (int t=0;t<5;t++) h2v[t] = gate_step(ac2[t], c2[t]);
        {
            const float o0=x3v[0]+h2v[0], o1=x3v[1]+h2v[1], o2=x3v[2]+h2v[2], o3=x3v[3]+h2v[3], o4=x3v[4]+h2v[4];
            x4ap[(size_t)l*TSTR] = make_uint2(pkf(o0,o1), pkf(o2,o3));
            x4bp[(size_t)l*TSTR] = f2h(o4);
        }
        half8 h2fn = packB(q, h2v[0],h2v[1],h2v[2],h2v[3],h2v[4], 0.f);

        // ---- LSTM1 step l+1
        float x2r[5] = { lo16(x2CurA.x), hi16(x2CurA.x), lo16(x2CurA.y), hi16(x2CurA.y), h2fl(x2CurB) };
        float s=0.f, ss=0.f;
#pragma unroll
        for (int t=0;t<5;t++){
            const float h = gate_step(ac1[t], c1[t]);
            h1v[t]=h;
            const float xv = x2r[t]+h;
            x3v[t]=xv; s+=xv; ss+=xv*xv;
        }
        half8 h1f = packB(q, h1v[0],h1v[1],h1v[2],h1v[3],h1v[4], 0.f);
        red4(s,ss);
        const float mn=s*0.05f; float var=fmaxf(ss*0.05f-mn*mn,0.f);
        const float rs=__builtin_amdgcn_rsqf(var+1e-5f), mr=mn*rs;
        half8 x3f = packB(q, x3v[0]*rs-mr, x3v[1]*rs-mr, x3v[2]*rs-mr, x3v[3]*rs-mr, x3v[4]*rs-mr, 1.0f);
        h2f = h2fn;

        // ---- issue ac2(l+1), ac1(l+2)
#pragma unroll
        for (int t=0;t<5;t++){
            ac2[t] = __builtin_amdgcn_mfma_f32_16x16x32_f16(Aa2[t],  x3f, Z, 0,0,0);
            ac2[t] = __builtin_amdgcn_mfma_f32_16x16x32_f16(Ahh2[t], h2f, ac2[t], 0,0,0);
        }
        const half8 xnf = __builtin_bit_cast(half8, xnCur);
#pragma unroll
        for (int t=0;t<5;t++){
            ac1[t] = __builtin_amdgcn_mfma_f32_16x16x32_f16(Aih1[t], xnf, Z, 0,0,0);
            ac1[t] = __builtin_amdgcn_mfma_f32_16x16x32_f16(Ahh1[t], h1f, ac1[t], 0,0,0);
        }
        xnCur = xnNxt;  xnNxt = xnNew;
        x2CurA = x2NxtA; x2CurB = x2NxtB;
        x2NxtA = x2NewA; x2NxtB = x2NewB;
    }
    // ---- epilogue: LSTM2 step 127
#pragma unroll
    for (int t=0;t<5;t++) h2v[t] = gate_step(ac2[t], c2[t]);
    {
        const float o0=x3v[0]+h2v[0], o1=x3v[1]+h2v[1], o2=x3v[2]+h2v[2], o3=x3v[3]+h2v[3], o4=x3v[4]+h2v[4];
        x4ap[(size_t)127*TSTR] = make_uint2(pkf(o0,o1), pkf(o2,o3));
        x4bp[(size_t)127*TSTR] = f2h(o4);
    }
}

// ---------------------------------------------------------------- kernel 3: POST (8 tiles/wave)
__global__ __launch_bounds__(256) void k_post(
    const uint2* __restrict__ x4a, const ushort* __restrict__ x4b,
    const float* __restrict__ g4, const float* __restrict__ w3, const float* __restrict__ b3,
    const float* __restrict__ g5, const float* __restrict__ w4, const float* __restrict__ b4,
    const float* __restrict__ g6, const float* __restrict__ w5, const float* __restrict__ b5,
    const float* __restrict__ wfw, const float* __restrict__ wfb,
    const float* __restrict__ sfw, const float* __restrict__ sfb,
    const float* __restrict__ dfw, const float* __restrict__ dfb,
    float* __restrict__ out)
{
    const int tid  = threadIdx.x;
    const int lane = tid & 63;
    const int col  = lane & 15, q = lane >> 4;
    const int wv   = blockIdx.x*4 + (tid>>6);
    const f32x4 Z  = {0.f,0.f,0.f,0.f};

    half8 A3[2], A4[2], A5[2];
#pragma unroll
    for (int tt=0;tt<2;tt++){
        const int u = uemap(tt, col);
        H8 a3,a4,a5;
#pragma unroll
        for (int j=0;j<8;j++){
            float v3=0.f,v4=0.f,v5=0.f;
            if (u>=0){
                if (j<5){
                    const int un=4*j+q;
                    v3=w3[u*20+un]*g4[un]; v4=w4[u*20+un]*g5[un]; v5=w5[u*20+un]*g6[un];
                } else if (j==5 && q==0){ v3=b3[u]; v4=b4[u]; v5=b5[u]; }
            }
            a3.s[j]=f2h(v3); a4.s[j]=f2h(v4); a5.s[j]=f2h(v5);
        }
        A3[tt]=a3.v; A4[tt]=a4.v; A5[tt]=a5.v;
    }
    half8 Ahd;
    {
        const int m=col, hd=m>>2, jh=m&3;
        const float* Wp = (hd==0)? wfw : (hd==1)? sfw : dfw;
        const float* Bp = (hd==0)? wfb : (hd==1)? sfb : dfb;
        const bool ok = (hd<3)&&(jh<3);
        H8 a;
#pragma unroll
        for (int j=0;j<8;j++){
            float v=0.f;
            if (ok){
                if (j<5) v=Wp[jh*20+4*j+q];
                else if (j==5 && q==0) v=Bp[jh];
            }
            a.s[j]=f2h(v);
        }
        Ahd=a.v;
    }

#pragma unroll 1
    for (int i=0;i<TPW;i++){
        const int tile = wv*TPW + i;
        const int l = tile>>9, nt = tile&511;

        const uint2  pa = x4a[(size_t)tile*64 + lane];
        const ushort pb = x4b[(size_t)tile*64 + lane];
        float x4[5] = { lo16(pa.x), hi16(pa.x), lo16(pa.y), hi16(pa.y), h2fl(pb) };

        float s=0.f, ss=0.f;
#pragma unroll
        for (int t=0;t<5;t++){ s+=x4[t]; ss+=x4[t]*x4[t]; }
        red4(s,ss);
        float mn=s*0.05f, var=fmaxf(ss*0.05f-mn*mn,0.f);
        float rs=__builtin_amdgcn_rsqf(var+1e-5f), mr=mn*rs;
        half8 f4 = packB(q, x4[0]*rs-mr, x4[1]*rs-mr, x4[2]*rs-mr, x4[3]*rs-mr, x4[4]*rs-mr, 1.0f);
        f32x4 c0 = __builtin_amdgcn_mfma_f32_16x16x32_f16(A3[0], f4, Z, 0,0,0);
        f32x4 c1 = __builtin_amdgcn_mfma_f32_16x16x32_f16(A3[1], f4, Z, 0,0,0);
        float hh[5]; s=0.f; ss=0.f;
#pragma unroll
        for (int t=0;t<5;t++){ hh[t]=siluf(t<4?c0[t]:c1[0]); s+=hh[t]; ss+=hh[t]*hh[t]; }
        red4(s,ss);
        mn=s*0.05f; var=fmaxf(ss*0.05f-mn*mn,0.f);
        rs=__builtin_amdgcn_rsqf(var+1e-5f); mr=mn*rs;
        half8 f5 = packB(q, hh[0]*rs-mr, hh[1]*rs-mr, hh[2]*rs-mr, hh[3]*rs-mr, hh[4]*rs-mr, 1.0f);
        c0 = __builtin_amdgcn_mfma_f32_16x16x32_f16(A4[0], f5, Z, 0,0,0);
        c1 = __builtin_amdgcn_mfma_f32_16x16x32_f16(A4[1], f5, Z, 0,0,0);
        float xp[5]; s=0.f; ss=0.f;
#pragma unroll
        for (int t=0;t<5;t++){ xp[t]=x4[t]+siluf(t<4?c0[t]:c1[0]); s+=xp[t]; ss+=xp[t]*xp[t]; }
        red4(s,ss);
        mn=s*0.05f; var=fmaxf(ss*0.05f-mn*mn,0.f);
        rs=__builtin_amdgcn_rsqf(var+1e-5f); mr=mn*rs;
        half8 f6 = packB(q, xp[0]*rs-mr, xp[1]*rs-mr, xp[2]*rs-mr, xp[3]*rs-mr, xp[4]*rs-mr, 1.0f);
        c0 = __builtin_amdgcn_mfma_f32_16x16x32_f16(A5[0], f6, Z, 0,0,0);
        c1 = __builtin_amdgcn_mfma_f32_16x16x32_f16(A5[1], f6, Z, 0,0,0);
        float xfv[5];
#pragma unroll
        for (int t=0;t<5;t++) xfv[t]=siluf(t<4?c0[t]:c1[0]);
        half8 fh = packB(q, xfv[0],xfv[1],xfv[2],xfv[3],xfv[4], 1.0f);
        const f32x4 ch = __builtin_amdgcn_mfma_f32_16x16x32_f16(Ahd, fh, Z, 0,0,0);

        if (q<3){
            const size_t base = (size_t)q*T3 + ((size_t)l*8192 + (size_t)nt*16 + col)*3;
            if (q==0){
                const float mx=fmaxf(ch[0],fmaxf(ch[1],ch[2]));
                const float e0=__expf(ch[0]-mx), e1=__expf(ch[1]-mx), e2=__expf(ch[2]-mx);
                const float inv=1.f/(e0+e1+e2);
                out[base+0]=e0*inv; out[base+1]=e1*inv; out[base+2]=e2*inv;
            } else {
                out[base+0]=__expf(fminf(fmaxf(ch[0],-25.f),25.f));
                out[base+1]=__expf(fminf(fmaxf(ch[1],-25.f),25.f));
                out[base+2]=__expf(fminf(fmaxf(ch[2],-25.f),25.f));
            }
        }
    }
}

// ---------------------------------------------------------------- launch
extern "C" void kernel_launch(void* const* d_in, const int* in_sizes, int n_in,
                              void* d_out, int out_size, void* d_ws, size_t ws_size,
                              hipStream_t stream)
{
    (void)in_sizes; (void)n_in; (void)out_size; (void)ws_size;
    const float* xlni  = (const float*)d_in[0];
    const float* imean = (const float*)d_in[1];
    const float* istd  = (const float*)d_in[2];
    const float* l1w = (const float*)d_in[3];
    const float* l1b = (const float*)d_in[4];
    const float* g1  = (const float*)d_in[5];
    const float* l2w = (const float*)d_in[6];
    const float* l2b = (const float*)d_in[7];
    const float* g2  = (const float*)d_in[8];
    const float* wih1=(const float*)d_in[9];
    const float* whh1=(const float*)d_in[10];
    const float* bih1=(const float*)d_in[11];
    const float* bhh1=(const float*)d_in[12];
    const float* g3  =(const float*)d_in[13];
    const float* b3n =(const float*)d_in[14];
    const float* wih2=(const float*)d_in[15];
    const float* whh2=(const float*)d_in[16];
    const float* bih2=(const float*)d_in[17];
    const float* bhh2=(const float*)d_in[18];
    const float* g4  =(const float*)d_in[19];
    const float* l3w =(const float*)d_in[20];
    const float* l3b =(const float*)d_in[21];
    const float* g5  =(const float*)d_in[22];
    const float* l4w =(const float*)d_in[23];
    const float* l4b =(const float*)d_in[24];
    const float* g6  =(const float*)d_in[25];
    const float* l5w =(const float*)d_in[26];
    const float* l5b =(const float*)d_in[27];
    const float* wfw =(const float*)d_in[28];
    const float* wfb =(const float*)d_in[29];
    const float* sfw =(const float*)d_in[30];
    const float* sfb =(const float*)d_in[31];
    const float* dfw =(const float*)d_in[32];
    const float* dfb =(const float*)d_in[33];

    uint4* xnfrag = (uint4*)d_ws;                                  // NWT*64*16B = 64 MiB
    uint2* x4a    = (uint2*)((char*)d_ws + 67108864ull);           // NWT*64*8B  = 32 MiB (x2 then x4)
    ushort* x4b   = (ushort*)((char*)d_ws + 100663296ull);         // NWT*64*2B  =  8 MiB

    k_pre <<<NWT/(4*TPW), 256, 0, stream>>>(xlni, imean, istd, l1w, l1b, g1, l2w, l2b,
                                            xnfrag, x4a, x4b);
    k_scan<<<NTL, 64, 0, stream>>>(xnfrag, x4a, x4b, g2,
                                   wih1, whh1, bih1, bhh1, g3, b3n,
                                   wih2, whh2, bih2, bhh2);
    k_post<<<NWT/(4*TPW), 256, 0, stream>>>(x4a, x4b, g4, l3w, l3b, g5, l4w, l4b, g6, l5w, l5b,
                                            wfw, wfb, sfw, sfb, dfw, dfb, (float*)d_out);
}

// Round 7
// 333.978 us; speedup vs baseline: 1.5064x; 1.2006x over previous
//
#include <hip/hip_runtime.h>
#include <hip/hip_fp16.h>

#define SEQ    128
#define NTL    512               /* n-tiles of 16 */
#define TOT    (SEQ*8192)        /* 1048576 */
#define T3     (TOT*3)

typedef __attribute__((ext_vector_type(8))) _Float16 half8;
typedef __attribute__((ext_vector_type(4))) float    f32x4;
union H8 { half8 v; ushort s[8]; uint u[4]; };

__device__ __forceinline__ float siluf(float x){ return x/(1.f+__expf(-x)); }
__device__ __forceinline__ ushort f2h(float x){ _Float16 h=(_Float16)x; return __builtin_bit_cast(ushort,h); }
__device__ __forceinline__ float  h2fl(ushort u){ _Float16 h=__builtin_bit_cast(_Float16,u); return (float)h; }
__device__ __forceinline__ float  lo16(uint u){ return h2fl((ushort)(u&0xFFFFu)); }
__device__ __forceinline__ float  hi16(uint u){ return h2fl((ushort)(u>>16)); }
__device__ __forceinline__ uint   pkf(float a, float b){ auto r=__builtin_amdgcn_cvt_pkrtz(a,b); return __builtin_bit_cast(uint,r); }

// K-slot permutation: k-slot 8g+j holds unit 4j+g (j<5); bias at k-slot 5 (g=0,j=5).
// MFMA C-layout (reg t -> unit 4t+q) IS the next B-layout: per-lane pack, no transpose.
__device__ __forceinline__ half8 packB(int q, float v0,float v1,float v2,float v3,float v4,float vb){
    H8 o;
    o.u[0]=pkf(v0,v1);
    o.u[1]=pkf(v2,v3);
    o.u[2]=pkf(v4, (q==0)? vb : 0.f);
    o.u[3]=0u;
    return o.v;
}

// gates pre-scaled by -1/ln2 (-2/ln2 for g row): pure exp2/rcp
__device__ __forceinline__ float gate_step(const f32x4 a, float& c){
    const float ei=__builtin_amdgcn_exp2f(a[0]);
    const float ef=__builtin_amdgcn_exp2f(a[1]);
    const float eg=__builtin_amdgcn_exp2f(a[2]);
    const float eo=__builtin_amdgcn_exp2f(a[3]);
    const float gi=__builtin_amdgcn_rcpf(1.f+ei);
    const float gf=__builtin_amdgcn_rcpf(1.f+ef);
    const float gg=2.f*__builtin_amdgcn_rcpf(1.f+eg)-1.f;
    const float go=__builtin_amdgcn_rcpf(1.f+eo);
    c = gf*c + gi*gg;
    const float ec=__builtin_amdgcn_exp2f(-2.885390082f*c);
    return go*(2.f*__builtin_amdgcn_rcpf(1.f+ec)-1.f);
}

__device__ __forceinline__ void red4(float& s, float& ss){
    s  += __shfl_xor(s,16,64);  s  += __shfl_xor(s,32,64);
    ss += __shfl_xor(ss,16,64); ss += __shfl_xor(ss,32,64);
}

// 20-row GEMV tile row->unit maps (C reg r of tile0 = unit 4r+q; tile1 reg0 = unit 16+q)
__device__ __forceinline__ int uemap(int tt, int m){
    if (tt==0) return 4*(m&3)+(m>>2);
    return ((m&3)==0) ? 16+(m>>2) : -1;
}

// ---------------------------------------------------------------- single fused kernel
// Block = 4 waves, one n-tile for all 128 steps. Wave 0: PRE (1 step ahead).
// Wave 1: LSTM1. Wave 2: LSTM2. Wave 3: POST+heads (3 steps behind).
// Double-buffered LDS slots; 1 barrier/iteration; each wave executes exactly
// SEQ+3 barriers (divergent-loop barrier structure — validated in R4).
__global__ __launch_bounds__(256) void k_all(
    const float* __restrict__ xlni, const float* __restrict__ imean, const float* __restrict__ istd,
    const float* __restrict__ w1,  const float* __restrict__ b1,  const float* __restrict__ g1,
    const float* __restrict__ w2,  const float* __restrict__ b2,  const float* __restrict__ g2,
    const float* __restrict__ wih1, const float* __restrict__ whh1,
    const float* __restrict__ bih1, const float* __restrict__ bhh1,
    const float* __restrict__ ln3g, const float* __restrict__ ln3b,
    const float* __restrict__ wih2, const float* __restrict__ whh2,
    const float* __restrict__ bih2, const float* __restrict__ bhh2,
    const float* __restrict__ g4, const float* __restrict__ w3, const float* __restrict__ b3,
    const float* __restrict__ g5, const float* __restrict__ w4, const float* __restrict__ b4,
    const float* __restrict__ g6, const float* __restrict__ w5, const float* __restrict__ b5,
    const float* __restrict__ wfw, const float* __restrict__ wfb,
    const float* __restrict__ sfw, const float* __restrict__ sfb,
    const float* __restrict__ dfw, const float* __restrict__ dfb,
    float* __restrict__ out)
{
    __shared__ uint4 preF[2][64];   // xn B-fragment (bias slot incl.)
    __shared__ uint2 preXa[2][64];  // x2 packed halves 0..3
    __shared__ uint  preXb[2][64];  // x2[4]
    __shared__ uint4 x3F[2][64];    // ln3(x3) B-fragment (bias slot incl.)
    __shared__ uint2 x3Xa[2][64];   // raw x3 0..3
    __shared__ uint  x3Xb[2][64];   // raw x3[4]
    __shared__ uint2 x4Xa[2][64];   // x4 0..3
    __shared__ uint  x4Xb[2][64];   // x4[4]

    const int tid  = threadIdx.x;
    const int wv   = tid >> 6;
    const int lane = tid & 63;
    const int col  = lane & 15, q = lane >> 4;
    const int nt   = blockIdx.x;
    const f32x4 Z  = {0.f,0.f,0.f,0.f};

    if (wv == 0){
        // ================= WAVE 0: PRE =================
        float wd[5], wu[5], ws0[5], ws1[5], ws2[5], ws3[5];
#pragma unroll
        for (int t=0;t<5;t++){
            const int u = 4*t+q;
            wd[t]=w1[u*6+0]; wu[t]=w1[u*6+1];
            ws0[t]=w1[u*6+2]+b1[u]; ws1[t]=w1[u*6+3]+b1[u];
            ws2[t]=w1[u*6+4]+b1[u]; ws3[t]=w1[u*6+5]+b1[u];
        }
        half8 Aw2[2];
#pragma unroll
        for (int tt=0;tt<2;tt++){
            const int u = uemap(tt, col);
            H8 a;
#pragma unroll
            for (int j=0;j<8;j++){
                float v=0.f;
                if (u>=0){
                    if (j<5){ const int un=4*j+q; v = w2[u*20+un]*g1[un]; }
                    else if (j==5 && q==0) v = b2[u];
                }
                a.s[j]=f2h(v);
            }
            Aw2[tt]=a.v;
        }
        const float mu0=imean[0], mu1=imean[1];
        const float ri0=1.f/istd[0], ri1=1.f/istd[1];

        float d0c,d1c,rc, d0n,d1n,rn;
        {
            const size_t ib0 = ((size_t)0*8192 + (size_t)nt*16 + col)*3;
            d0c=xlni[ib0]; d1c=xlni[ib0+1]; rc=xlni[ib0+2];
            const size_t ib1 = ((size_t)1*8192 + (size_t)nt*16 + col)*3;
            d0n=xlni[ib1]; d1n=xlni[ib1+1]; rn=xlni[ib1+2];
        }
#pragma unroll 1
        for (int i=0;i<SEQ+3;i++){
            if (i<SEQ){
                const float D0=d0c, D1=d1c, RR=rc;
                d0c=d0n; d1c=d1n; rc=rn;
                const int lp = (i+2<SEQ)? i+2 : SEQ-1;
                const size_t ibn = ((size_t)lp*8192 + (size_t)nt*16 + col)*3;
                d0n=xlni[ibn]; d1n=xlni[ibn+1]; rn=xlni[ibn+2];

                const float xd = (__logf(1e-5f+D0)-mu0)*ri0;
                const float xu = (__logf(fminf(fmaxf(D1,100.f),60000.f))-mu1)*ri1;
                int r = (int)fmaxf(RR,1.f)-1; r = r<0?0:(r>3?3:r);

                float av[5], s=0.f, ss=0.f;
#pragma unroll
                for (int t=0;t<5;t++){
                    const float wsel = (r==0)?ws0[t]:(r==1)?ws1[t]:(r==2)?ws2[t]:ws3[t];
                    const float v = wd[t]*xd + wu[t]*xu + wsel;
                    av[t]=siluf(v); s+=av[t]; ss+=av[t]*av[t];
                }
                red4(s,ss);
                float mn=s*0.05f, var=fmaxf(ss*0.05f-mn*mn,0.f);
                float rs=__builtin_amdgcn_rsqf(var+1e-5f); float mr=mn*rs;
                const half8 yf = packB(q, av[0]*rs-mr, av[1]*rs-mr, av[2]*rs-mr, av[3]*rs-mr, av[4]*rs-mr, 1.0f);
                const f32x4 c0 = __builtin_amdgcn_mfma_f32_16x16x32_f16(Aw2[0], yf, Z, 0,0,0);
                const f32x4 c1 = __builtin_amdgcn_mfma_f32_16x16x32_f16(Aw2[1], yf, Z, 0,0,0);
                float X2[5]; s=0.f; ss=0.f;
#pragma unroll
                for (int t=0;t<5;t++){
                    const float v = siluf(t<4 ? c0[t] : c1[0]);
                    X2[t]=v; s+=v; ss+=v*v;
                }
                red4(s,ss);
                mn=s*0.05f; var=fmaxf(ss*0.05f-mn*mn,0.f);
                rs=__builtin_amdgcn_rsqf(var+1e-5f); mr=mn*rs;
                const half8 xnf = packB(q, X2[0]*rs-mr, X2[1]*rs-mr, X2[2]*rs-mr, X2[3]*rs-mr, X2[4]*rs-mr, 1.0f);

                H8 fo; fo.v = xnf;
                const int sl = i&1;
                preF [sl][lane] = make_uint4(fo.u[0],fo.u[1],fo.u[2],fo.u[3]);
                preXa[sl][lane] = make_uint2(pkf(X2[0],X2[1]), pkf(X2[2],X2[3]));
                preXb[sl][lane] = pkf(X2[4],0.f);
            }
            __syncthreads();
        }
    } else if (wv == 1){
        // ================= WAVE 1: LSTM1 =================
        half8 Aih1[5], Ahh1[5];
#pragma unroll
        for (int t=0;t<5;t++){
            const int M = t*16 + col, u = M>>2, g = M&3, r = g*20+u;
            const float sc = (g==2)? -2.885390082f : -1.442695041f;
            H8 a0,a1;
#pragma unroll
            for (int j=0;j<8;j++){
                float vih1=0.f, vhh1=0.f;
                if (j<5){
                    const int un = 4*j+q;
                    vih1 = wih1[r*20+un]*g2[un]*sc;
                    vhh1 = whh1[r*20+un]*sc;
                } else if (j==5 && q==0){
                    vih1 = (bih1[r]+bhh1[r])*sc;
                }
                a0.s[j]=f2h(vih1); a1.s[j]=f2h(vhh1);
            }
            Aih1[t]=a0.v; Ahh1[t]=a1.v;
        }
        float c1[5]={0,0,0,0,0};
        half8 h1f; { H8 z; z.u[0]=0;z.u[1]=0;z.u[2]=0;z.u[3]=0; h1f=z.v; }

#pragma unroll 1
        for (int i=0;i<SEQ+3;i++){
            if (i>=1 && i<SEQ+1){
                const int sl = (i-1)&1;
                const uint4 fr = preF[sl][lane];
                const uint2 xa = preXa[sl][lane];
                const uint  xb = preXb[sl][lane];
                H8 fi; fi.u[0]=fr.x; fi.u[1]=fr.y; fi.u[2]=fr.z; fi.u[3]=fr.w;
                f32x4 ac[5];
#pragma unroll
                for (int t=0;t<5;t++){
                    ac[t] = __builtin_amdgcn_mfma_f32_16x16x32_f16(Aih1[t], fi.v, Z, 0,0,0);
                    ac[t] = __builtin_amdgcn_mfma_f32_16x16x32_f16(Ahh1[t], h1f, ac[t], 0,0,0);
                }
                const float x2r[5] = { lo16(xa.x), hi16(xa.x), lo16(xa.y), hi16(xa.y), lo16(xb) };
                float x3v[5], h1v[5], s=0.f, ss=0.f;
#pragma unroll
                for (int t=0;t<5;t++){
                    const float h = gate_step(ac[t], c1[t]);
                    h1v[t]=h;
                    const float xv = x2r[t]+h;
                    x3v[t]=xv; s+=xv; ss+=xv*xv;
                }
                h1f = packB(q, h1v[0],h1v[1],h1v[2],h1v[3],h1v[4], 0.f);
                red4(s,ss);
                const float mn=s*0.05f; float var=fmaxf(ss*0.05f-mn*mn,0.f);
                const float rs=__builtin_amdgcn_rsqf(var+1e-5f), mr=mn*rs;
                const half8 x3f = packB(q, x3v[0]*rs-mr, x3v[1]*rs-mr, x3v[2]*rs-mr, x3v[3]*rs-mr, x3v[4]*rs-mr, 1.0f);
                H8 fo; fo.v = x3f;
                x3F [sl][lane] = make_uint4(fo.u[0],fo.u[1],fo.u[2],fo.u[3]);
                x3Xa[sl][lane] = make_uint2(pkf(x3v[0],x3v[1]), pkf(x3v[2],x3v[3]));
                x3Xb[sl][lane] = pkf(x3v[4],0.f);
            }
            __syncthreads();
        }
    } else if (wv == 2){
        // ================= WAVE 2: LSTM2 =================
        half8 Aa2[5], Ahh2[5];
#pragma unroll
        for (int t=0;t<5;t++){
            const int M = t*16 + col, u = M>>2, g = M&3, r = g*20+u;
            const float sc = (g==2)? -2.885390082f : -1.442695041f;
            H8 a0,a1;
#pragma unroll
            for (int j=0;j<8;j++){
                float va2=0.f, vhh2=0.f;
                if (j<5){
                    const int un = 4*j+q;
                    va2  = wih2[r*20+un]*ln3g[un]*sc;
                    vhh2 = whh2[r*20+un]*sc;
                } else if (j==5 && q==0){
                    float b2 = bih2[r]+bhh2[r];
                    for (int kk=0;kk<20;kk++) b2 += wih2[r*20+kk]*ln3b[kk];
                    va2 = b2*sc;
                }
                a0.s[j]=f2h(va2); a1.s[j]=f2h(vhh2);
            }
            Aa2[t]=a0.v; Ahh2[t]=a1.v;
        }
        float c2[5]={0,0,0,0,0};
        half8 h2f; { H8 z; z.u[0]=0;z.u[1]=0;z.u[2]=0;z.u[3]=0; h2f=z.v; }

#pragma unroll 1
        for (int i=0;i<SEQ+3;i++){
            if (i>=2 && i<SEQ+2){
                const int sl = (i-2)&1;
                const uint4 fr = x3F[sl][lane];
                const uint2 xa = x3Xa[sl][lane];
                const uint  xb = x3Xb[sl][lane];
                H8 fi; fi.u[0]=fr.x; fi.u[1]=fr.y; fi.u[2]=fr.z; fi.u[3]=fr.w;
                f32x4 ac[5];
#pragma unroll
                for (int t=0;t<5;t++){
                    ac[t] = __builtin_amdgcn_mfma_f32_16x16x32_f16(Aa2[t],  fi.v, Z, 0,0,0);
                    ac[t] = __builtin_amdgcn_mfma_f32_16x16x32_f16(Ahh2[t], h2f, ac[t], 0,0,0);
                }
                const float x3v[5] = { lo16(xa.x), hi16(xa.x), lo16(xa.y), hi16(xa.y), lo16(xb) };
                float h2v[5], x4[5];
#pragma unroll
                for (int t=0;t<5;t++){
                    h2v[t] = gate_step(ac[t], c2[t]);
                    x4[t]  = x3v[t] + h2v[t];
                }
                h2f = packB(q, h2v[0],h2v[1],h2v[2],h2v[3],h2v[4], 0.f);
                x4Xa[sl][lane] = make_uint2(pkf(x4[0],x4[1]), pkf(x4[2],x4[3]));
                x4Xb[sl][lane] = pkf(x4[4],0.f);
            }
            __syncthreads();
        }
    } else {
        // ================= WAVE 3: POST + heads =================
        half8 A3[2], A4[2], A5[2];
#pragma unroll
        for (int tt=0;tt<2;tt++){
            const int u = uemap(tt, col);
            H8 a3,a4,a5;
#pragma unroll
            for (int j=0;j<8;j++){
                float v3=0.f,v4=0.f,v5=0.f;
                if (u>=0){
                    if (j<5){
                        const int un=4*j+q;
                        v3=w3[u*20+un]*g4[un]; v4=w4[u*20+un]*g5[un]; v5=w5[u*20+un]*g6[un];
                    } else if (j==5 && q==0){ v3=b3[u]; v4=b4[u]; v5=b5[u]; }
                }
                a3.s[j]=f2h(v3); a4.s[j]=f2h(v4); a5.s[j]=f2h(v5);
            }
            A3[tt]=a3.v; A4[tt]=a4.v; A5[tt]=a5.v;
        }
        half8 Ahd;
        {
            const int m=col, hd=m>>2, jh=m&3;
            const float* Wp = (hd==0)? wfw : (hd==1)? sfw : dfw;
            const float* Bp = (hd==0)? wfb : (hd==1)? sfb : dfb;
            const bool ok = (hd<3)&&(jh<3);
            H8 a;
#pragma unroll
            for (int j=0;j<8;j++){
                float v=0.f;
                if (ok){
                    if (j<5) v=Wp[jh*20+4*j+q];
                    else if (j==5 && q==0) v=Bp[jh];
                }
                a.s[j]=f2h(v);
            }
            Ahd=a.v;
        }

#pragma unroll 1
        for (int i=0;i<SEQ+3;i++){
            if (i>=3){
                const int st = i-3;
                const int sl = st&1;
                const uint2 pa = x4Xa[sl][lane];
                const uint  pb = x4Xb[sl][lane];
                float x4[5] = { lo16(pa.x), hi16(pa.x), lo16(pa.y), hi16(pa.y), lo16(pb) };

                float s=0.f, ss=0.f;
#pragma unroll
                for (int t=0;t<5;t++){ s+=x4[t]; ss+=x4[t]*x4[t]; }
                red4(s,ss);
                float mn=s*0.05f, var=fmaxf(ss*0.05f-mn*mn,0.f);
                float rs=__builtin_amdgcn_rsqf(var+1e-5f), mr=mn*rs;
                half8 f4 = packB(q, x4[0]*rs-mr, x4[1]*rs-mr, x4[2]*rs-mr, x4[3]*rs-mr, x4[4]*rs-mr, 1.0f);
                f32x4 c0 = __builtin_amdgcn_mfma_f32_16x16x32_f16(A3[0], f4, Z, 0,0,0);
                f32x4 c1 = __builtin_amdgcn_mfma_f32_16x16x32_f16(A3[1], f4, Z, 0,0,0);
                float hh[5]; s=0.f; ss=0.f;
#pragma unroll
                for (int t=0;t<5;t++){ hh[t]=siluf(t<4?c0[t]:c1[0]); s+=hh[t]; ss+=hh[t]*hh[t]; }
                red4(s,ss);
                mn=s*0.05f; var=fmaxf(ss*0.05f-mn*mn,0.f);
                rs=__builtin_amdgcn_rsqf(var+1e-5f); mr=mn*rs;
                half8 f5 = packB(q, hh[0]*rs-mr, hh[1]*rs-mr, hh[2]*rs-mr, hh[3]*rs-mr, hh[4]*rs-mr, 1.0f);
                c0 = __builtin_amdgcn_mfma_f32_16x16x32_f16(A4[0], f5, Z, 0,0,0);
                c1 = __builtin_amdgcn_mfma_f32_16x16x32_f16(A4[1], f5, Z, 0,0,0);
                float xp[5]; s=0.f; ss=0.f;
#pragma unroll
                for (int t=0;t<5;t++){ xp[t]=x4[t]+siluf(t<4?c0[t]:c1[0]); s+=xp[t]; ss+=xp[t]*xp[t]; }
                red4(s,ss);
                mn=s*0.05f; var=fmaxf(ss*0.05f-mn*mn,0.f);
                rs=__builtin_amdgcn_rsqf(var+1e-5f); mr=mn*rs;
                half8 f6 = packB(q, xp[0]*rs-mr, xp[1]*rs-mr, xp[2]*rs-mr, xp[3]*rs-mr, xp[4]*rs-mr, 1.0f);
                c0 = __builtin_amdgcn_mfma_f32_16x16x32_f16(A5[0], f6, Z, 0,0,0);
                c1 = __builtin_amdgcn_mfma_f32_16x16x32_f16(A5[1], f6, Z, 0,0,0);
                float xfv[5];
#pragma unroll
                for (int t=0;t<5;t++) xfv[t]=siluf(t<4?c0[t]:c1[0]);
                half8 fh = packB(q, xfv[0],xfv[1],xfv[2],xfv[3],xfv[4], 1.0f);
                const f32x4 ch = __builtin_amdgcn_mfma_f32_16x16x32_f16(Ahd, fh, Z, 0,0,0);

                if (q<3){
                    const size_t base = (size_t)q*T3 + ((size_t)st*8192 + (size_t)nt*16 + col)*3;
                    if (q==0){
                        const float mx=fmaxf(ch[0],fmaxf(ch[1],ch[2]));
                        const float e0=__expf(ch[0]-mx), e1=__expf(ch[1]-mx), e2=__expf(ch[2]-mx);
                        const float inv=1.f/(e0+e1+e2);
                        out[base+0]=e0*inv; out[base+1]=e1*inv; out[base+2]=e2*inv;
                    } else {
                        out[base+0]=__expf(fminf(fmaxf(ch[0],-25.f),25.f));
                        out[base+1]=__expf(fminf(fmaxf(ch[1],-25.f),25.f));
                        out[base+2]=__expf(fminf(fmaxf(ch[2],-25.f),25.f));
                    }
                }
            }
            __syncthreads();
        }
    }
}

// ---------------------------------------------------------------- launch
extern "C" void kernel_launch(void* const* d_in, const int* in_sizes, int n_in,
                              void* d_out, int out_size, void* d_ws, size_t ws_size,
                              hipStream_t stream)
{
    (void)in_sizes; (void)n_in; (void)out_size; (void)d_ws; (void)ws_size;
    const float* xlni  = (const float*)d_in[0];
    const float* imean = (const float*)d_in[1];
    const float* istd  = (const float*)d_in[2];
    const float* l1w = (const float*)d_in[3];
    const float* l1b = (const float*)d_in[4];
    const float* g1  = (const float*)d_in[5];
    const float* l2w = (const float*)d_in[6];
    const float* l2b = (const float*)d_in[7];
    const float* g2  = (const float*)d_in[8];
    const float* wih1=(const float*)d_in[9];
    const float* whh1=(const float*)d_in[10];
    const float* bih1=(const float*)d_in[11];
    const float* bhh1=(const float*)d_in[12];
    const float* g3  =(const float*)d_in[13];
    const float* b3n =(const float*)d_in[14];
    const float* wih2=(const float*)d_in[15];
    const float* whh2=(const float*)d_in[16];
    const float* bih2=(const float*)d_in[17];
    const float* bhh2=(const float*)d_in[18];
    const float* g4  =(const float*)d_in[19];
    const float* l3w =(const float*)d_in[20];
    const float* l3b =(const float*)d_in[21];
    const float* g5  =(const float*)d_in[22];
    const float* l4w =(const float*)d_in[23];
    const float* l4b =(const float*)d_in[24];
    const float* g6  =(const float*)d_in[25];
    const float* l5w =(const float*)d_in[26];
    const float* l5b =(const float*)d_in[27];
    const float* wfw =(const float*)d_in[28];
    const float* wfb =(const float*)d_in[29];
    const float* sfw =(const float*)d_in[30];
    const float* sfb =(const float*)d_in[31];
    const float* dfw =(const float*)d_in[32];
    const float* dfb =(const float*)d_in[33];

    k_all<<<NTL, 256, 0, stream>>>(
        xlni, imean, istd,
        l1w, l1b, g1, l2w, l2b, g2,
        wih1, whh1, bih1, bhh1, g3, b3n,
        wih2, whh2, bih2, bhh2,
        g4, l3w, l3b, g5, l4w, l4b, g6, l5w, l5b,
        wfw, wfb, sfw, sfb, dfw, dfb,
        (float*)d_out);
}